// Round 11
// baseline (1713.637 us; speedup 1.0000x reference)
//
#include <hip/hip_runtime.h>

// JTNN encoder, MI355X.
//  - hU = h @ Ur_w once per row, gathered (5x FLOP cut vs h_nei@Ur)
//  - h bf16 (fp8-h FAILED accuracy R7); hU fp8 e4m3 (validated safe R6)
//  - h + hU interleaved in ONE 768 B/row buffer HM (single random fetch/neighbor)
//  - R10: NT stores disproved write-pollution theory (FETCH unchanged, dur
//    slightly worse) -> reverted. fused_step is random-access LATENCY bound
//    (2.5 of 6.3 TB/s achievable). This round: LDS 33.8 -> 32 KiB via XOR
//    swizzle (no pad) -> 5 blocks/CU -> 20 waves/CU (+25% MLP)
//  - x-side projections folded into per-VOCAB tables (780 rows, L2-resident)
//  - depth-0 closed form: h1 = sigma(embZ[v]) * tanh(embH[v]); hU1 = (h1tab@Ur)[v]
//  - fused_step: gather + Z/P GEMM + GRU update + U-GEMM in ONE kernel
//  - gather_out: node-side gather + out-projection GEMM fused

#define HD 256
#define NNODES 65536
#define NMESS 131072
#define NVOCAB 780
#define NTREES 2048
#define MAXNEI 5
#define BMF 32
#define ROWB 768    // HM row bytes: 512 h-bf16 + 256 u-fp8

// XOR-swizzled LDS addressing: element (row, col) chunk c=col>>3 lives at
// row*256 + ((c ^ (row&7))<<3) + (col&7).  <=2-way bank aliasing (free).
#define SWZ16(row, chunk) ((row) * 256 + ((((chunk) ^ ((row) & 7))) << 3))

typedef short bfrag __attribute__((ext_vector_type(8)));   // 8 bf16 in 4 VGPRs
typedef short s16x8 __attribute__((ext_vector_type(8)));
typedef float f32x4v __attribute__((ext_vector_type(4)));
typedef float f32x2 __attribute__((ext_vector_type(2)));
typedef unsigned int u32x2 __attribute__((ext_vector_type(2)));
typedef unsigned short ush;
typedef unsigned char u8;

__device__ __forceinline__ float bf2f(ush u) {
    union { unsigned int u; float f; } v; v.u = ((unsigned int)u) << 16; return v.f;
}
__device__ __forceinline__ float bfu_lo(unsigned int w) {
    union { unsigned int u; float f; } v; v.u = w << 16; return v.f;
}
__device__ __forceinline__ float bfu_hi(unsigned int w) {
    union { unsigned int u; float f; } v; v.u = w & 0xffff0000u; return v.f;
}
__device__ __forceinline__ ush f2bf_fast(float f) {
    union { float f; unsigned int u; } v; v.f = f;
    return (ush)((v.u + 0x8000u) >> 16);
}
__device__ __forceinline__ unsigned int pack2bf(float hi, float lo) {
    union { float f; unsigned int u; } a, b; a.f = hi; b.f = lo;
    return __builtin_amdgcn_perm(a.u + 0x8000u, b.u + 0x8000u, 0x07060302u);
}
__device__ __forceinline__ float sigm(float x) {
    return __builtin_amdgcn_rcpf(1.f + __expf(-x));
}
__device__ __forceinline__ float tanh_fast(float x) {
    return 1.f - 2.f * __builtin_amdgcn_rcpf(__expf(2.f * x) + 1.f);
}
// 8 f32 -> 8 fp8 e4m3 packed in u32x2
__device__ __forceinline__ u32x2 pack8fp8(const float* f) {
    int lo = __builtin_amdgcn_cvt_pk_fp8_f32(f[0], f[1], 0, 0);
    lo = __builtin_amdgcn_cvt_pk_fp8_f32(f[2], f[3], lo, 1);
    int hi = __builtin_amdgcn_cvt_pk_fp8_f32(f[4], f[5], 0, 0);
    hi = __builtin_amdgcn_cvt_pk_fp8_f32(f[6], f[7], hi, 1);
    u32x2 o; o.x = (unsigned int)lo; o.y = (unsigned int)hi; return o;
}
// 8 fp8 e4m3 (u32x2) -> 8 f32
__device__ __forceinline__ void fp8x8_to_f32(u32x2 v, float* f) {
    f32x2 a = __builtin_amdgcn_cvt_pk_f32_fp8((int)v.x, false);
    f32x2 b = __builtin_amdgcn_cvt_pk_f32_fp8((int)v.x, true);
    f32x2 c = __builtin_amdgcn_cvt_pk_f32_fp8((int)v.y, false);
    f32x2 d = __builtin_amdgcn_cvt_pk_f32_fp8((int)v.y, true);
    f[0] = a.x; f[1] = a.y; f[2] = b.x; f[3] = b.y;
    f[4] = c.x; f[5] = c.y; f[6] = d.x; f[7] = d.y;
}

// ---------------- prep: vocab tables, split-k over 4 blocks (atomicAdd) -----
__global__ __launch_bounds__(256) void prep_tables_sk(
    const float* __restrict__ emb,
    const float* __restrict__ Wz_w, const float* __restrict__ Wz_b,
    const float* __restrict__ Wr_w, const float* __restrict__ Ur_b,
    const float* __restrict__ Wh_w, const float* __restrict__ Wh_b,
    const float* __restrict__ out_w, const float* __restrict__ out_b,
    float* __restrict__ embR, float* __restrict__ embZ,
    float* __restrict__ embH, float* __restrict__ embO)
{
    __shared__ __align__(16) float e[4][64];
    int t = threadIdx.x;
    int b0 = blockIdx.x * 4;
    int k0 = blockIdx.y * 64;
    e[t >> 6][t & 63] = emb[(b0 + (t >> 6)) * HD + k0 + (t & 63)];
    __syncthreads();
    float aR[4] = {0,0,0,0}, aZ[4] = {0,0,0,0}, aH[4] = {0,0,0,0}, aO[4] = {0,0,0,0};
    for (int kk = 0; kk < 64; kk++) {
        int k = k0 + kk;
        float wr = Wr_w[k * HD + t];
        float wz = Wz_w[k * HD + t];
        float wh = Wh_w[k * HD + t];
        float wo = out_w[k * HD + t];
        #pragma unroll
        for (int r = 0; r < 4; r++) {
            float ev = e[r][kk];
            aR[r] += ev * wr; aZ[r] += ev * wz; aH[r] += ev * wh; aO[r] += ev * wo;
        }
    }
    if (blockIdx.y == 0) {
        float br = Ur_b[t], bz = Wz_b[t], bh = Wh_b[t], bo = out_b[t];
        #pragma unroll
        for (int r = 0; r < 4; r++) { aR[r] += br; aZ[r] += bz; aH[r] += bh; aO[r] += bo; }
    }
    #pragma unroll
    for (int r = 0; r < 4; r++) {
        atomicAdd(&embR[(b0 + r) * HD + t], aR[r]);
        atomicAdd(&embZ[(b0 + r) * HD + t], aZ[r]);
        atomicAdd(&embH[(b0 + r) * HD + t], aH[r]);
        atomicAdd(&embO[(b0 + r) * HD + t], aO[r]);
    }
}

// h1tab[v] = sigmoid(embZ[v]) * tanh(embH[v])   (depth-0 closed form)
__global__ __launch_bounds__(256) void h1fill(
    const float* __restrict__ embZ, const float* __restrict__ embH,
    ush* __restrict__ h1tab)
{
    int i = blockIdx.x * HD + threadIdx.x;
    h1tab[i] = f2bf_fast(sigm(embZ[i]) * tanh_fast(embH[i]));
}

// embU[v] = h1tab[v] @ Ur_w  (780x256 rows, split-k atomic)
__global__ __launch_bounds__(256) void h1u_sk(
    const ush* __restrict__ h1tab, const float* __restrict__ Ur_w,
    float* __restrict__ embU)
{
    __shared__ __align__(16) float e[4][64];
    int t = threadIdx.x;
    int b0 = blockIdx.x * 4;
    int k0 = blockIdx.y * 64;
    e[t >> 6][t & 63] = bf2f(h1tab[(b0 + (t >> 6)) * HD + k0 + (t & 63)]);
    __syncthreads();
    float aU[4] = {0,0,0,0};
    for (int kk = 0; kk < 64; kk++) {
        float w = Ur_w[(k0 + kk) * HD + t];
        #pragma unroll
        for (int r = 0; r < 4; r++) aU[r] += e[r][kk] * w;
    }
    #pragma unroll
    for (int r = 0; r < 4; r++) atomicAdd(&embU[(b0 + r) * HD + t], aU[r]);
}

// weights: fragment-packed (Wz_p, Wh_p, Ur_p, Wo_p).
__global__ __launch_bounds__(256) void prep_wt(
    const float* __restrict__ Ur_w, const float* __restrict__ Wz_w,
    const float* __restrict__ Wh_w, const float* __restrict__ out_w,
    ush* __restrict__ Wo_p,
    ush* __restrict__ Wz_p, ush* __restrict__ Wh_p, ush* __restrict__ Ur_p)
{
    int idx = blockIdx.x * 256 + threadIdx.x;   // n*256 + k
    int n = idx >> 8, k = idx & 255;
    int paddr = ((((n >> 4) * 8 + (k >> 5)) * 64 + ((k >> 3) & 3) * 16 + (n & 15)) << 3) + (k & 7);
    Wo_p[paddr] = f2bf_fast(out_w[(HD + k) * HD + n]);
    Wz_p[paddr] = f2bf_fast(Wz_w[(HD + k) * HD + n]);
    Wh_p[paddr] = f2bf_fast(Wh_w[(HD + k) * HD + n]);
    Ur_p[paddr] = f2bf_fast(Ur_w[k * HD + n]);
}

__global__ __launch_bounds__(256) void prep_vmess(
    const int* __restrict__ fnode, const int* __restrict__ fmess,
    int* __restrict__ v_mess)
{
    int m = blockIdx.x * 256 + threadIdx.x;
    v_mess[m] = fnode[fmess[m]];
}

// depth-0 fill: HM row m = [h1tab[v] bf16 | fp8(embU[v])]; row 0 = 0
__global__ __launch_bounds__(256) void fill_h1(
    const ush* __restrict__ h1tab, const float* __restrict__ embU,
    const int* __restrict__ v_mess, u8* __restrict__ HM)
{
    int t = blockIdx.x * 256 + threadIdx.x;
    int m = t >> 5;
    int c = (t & 31) * 8;          // elem offset 0..248
    int v = v_mess[m];
    s16x8 o = *(const s16x8*)&h1tab[v * HD + c];
    float u[8];
    *(float4*)&u[0] = *(const float4*)&embU[v * HD + c];
    *(float4*)&u[4] = *(const float4*)&embU[v * HD + c + 4];
    u32x2 up = pack8fp8(u);
    if (m == 0) { o = (s16x8){0,0,0,0,0,0,0,0}; up.x = up.y = 0; }
    u8* row = HM + (size_t)m * ROWB;
    *(s16x8*)(row + 2 * c) = o;
    *(u32x2*)(row + 512 + c) = up;
}

// ---------------- fused step: gather + Z/P GEMM + GRU + U-GEMM --------------
// 32 messages/block, 256 threads (4 waves), LDS exactly 32 KiB -> 5 blocks/CU
// (20 waves/CU) for gather latency hiding.
template<int EMIT_HU>
__global__ __launch_bounds__(256, 5) void fused_step(
    const u8* __restrict__ HM, const int* __restrict__ mg,
    const int* __restrict__ v_mess,
    const float* __restrict__ embR, const float* __restrict__ embZ,
    const float* __restrict__ embH,
    const ush* __restrict__ Wz_p, const ush* __restrict__ Wh_p,
    const ush* __restrict__ Ur_p,
    u8* __restrict__ HM_next)
{
    __shared__ __align__(16) ush sh[BMF * 256];   // sum_h tile  (16 KiB, swizzled)
    __shared__ __align__(16) ush sg[BMF * 256];   // sum_gh -> h_next tile
    int tid = threadIdx.x;
    int wv = tid >> 6, lane = tid & 63;
    int quad = lane >> 4, l16 = lane & 15;
    int m0 = blockIdx.x * BMF;

    // ---- phase 1: gather + r-gate into LDS (one 768B row fetch/neighbor) ----
    #pragma unroll 2
    for (int it = 0; it < 4; it++) {
        int g = it * 256 + tid;
        int ml = g >> 5;               // 0..31
        int ch = g & 31;               // chunk 0..31; col c = ch*8
        int c = ch * 8;
        int m = m0 + ml;
        int v = v_mess[m];
        int jj[MAXNEI];
        #pragma unroll
        for (int kn = 0; kn < MAXNEI; kn++) jj[kn] = mg[m * MAXNEI + kn];
        float rb[8];
        *(float4*)&rb[0] = *(const float4*)&embR[v * HD + c];
        *(float4*)&rb[4] = *(const float4*)&embR[v * HD + c + 4];
        float ah[8] = {0,0,0,0,0,0,0,0};
        float ag[8] = {0,0,0,0,0,0,0,0};
        #pragma unroll
        for (int kn = 0; kn < MAXNEI; kn++) {
            const u8* row = HM + (size_t)jj[kn] * ROWB;
            s16x8 hv = *(const s16x8*)(row + 2 * c);
            u32x2 uv8 = *(const u32x2*)(row + 512 + c);
            float uf[8];
            fp8x8_to_f32(uv8, uf);
            #pragma unroll
            for (int e = 0; e < 8; e++) {
                float hf = bf2f((ush)hv[e]);
                ah[e] += hf;
                ag[e] += sigm(rb[e] + uf[e]) * hf;
            }
        }
        uint4 oh, og;
        oh.x = pack2bf(ah[1], ah[0]); oh.y = pack2bf(ah[3], ah[2]);
        oh.z = pack2bf(ah[5], ah[4]); oh.w = pack2bf(ah[7], ah[6]);
        og.x = pack2bf(ag[1], ag[0]); og.y = pack2bf(ag[3], ag[2]);
        og.z = pack2bf(ag[5], ag[4]); og.w = pack2bf(ag[7], ag[6]);
        *(uint4*)&sh[SWZ16(ml, ch)] = oh;
        *(uint4*)&sg[SWZ16(ml, ch)] = og;
    }
    __syncthreads();

    // ---- phase 2: Z = sum_h @ Wz2, P = sum_gh @ Wh2 (B frags from global) ----
    f32x4v az[2][4] = {}, ap[2][4] = {};
    #pragma unroll
    for (int ksi = 0; ksi < 8; ksi++) {
        bfrag ahf[2], agf[2], bz[4], bh[4];
        #pragma unroll
        for (int i = 0; i < 2; i++) {
            int rr = i * 16 + l16;
            int q = ksi * 4 + quad;
            ahf[i] = *(const bfrag*)&sh[SWZ16(rr, q)];
            agf[i] = *(const bfrag*)&sg[SWZ16(rr, q)];
        }
        #pragma unroll
        for (int j = 0; j < 4; j++) {
            int f = ((wv * 4 + j) * 8 + ksi) * 64 + lane;
            bz[j] = *(const bfrag*)&Wz_p[(size_t)f * 8];
            bh[j] = *(const bfrag*)&Wh_p[(size_t)f * 8];
        }
        #pragma unroll
        for (int i = 0; i < 2; i++)
            #pragma unroll
            for (int j = 0; j < 4; j++) {
                az[i][j] = __builtin_amdgcn_mfma_f32_16x16x32_bf16(ahf[i], bz[j], az[i][j], 0, 0, 0);
                ap[i][j] = __builtin_amdgcn_mfma_f32_16x16x32_bf16(agf[i], bh[j], ap[i][j], 0, 0, 0);
            }
    }

    // ---- GRU combine: az[i][j][r] <- h_next value (reuse regs) ----
    #pragma unroll
    for (int i = 0; i < 2; i++) {
        #pragma unroll
        for (int r = 0; r < 4; r++) {
            int rl = i * 16 + quad * 4 + r;
            int Rg = m0 + rl;
            int v = v_mess[Rg];
            #pragma unroll
            for (int j = 0; j < 4; j++) {
                int col = wv * 64 + j * 16 + l16;
                float z = sigm(az[i][j][r] + embZ[v * HD + col]);
                float pre = tanh_fast(ap[i][j][r] + embH[v * HD + col]);
                float shv = bf2f(sh[SWZ16(rl, col >> 3) + (col & 7)]);
                float hn = (1.f - z) * shv + z * pre;
                if (Rg == 0) hn = 0.f;
                az[i][j][r] = hn;
            }
        }
    }
    __syncthreads();   // all sh/sg reads done

    // ---- h_next tile into sg (LDS), then coalesced bf16 global write ----
    #pragma unroll
    for (int i = 0; i < 2; i++)
        #pragma unroll
        for (int j = 0; j < 4; j++) {
            int col = wv * 64 + j * 16 + l16;
            #pragma unroll
            for (int r = 0; r < 4; r++) {
                int rl = i * 16 + quad * 4 + r;
                sg[SWZ16(rl, col >> 3) + (col & 7)] = f2bf_fast(az[i][j][r]);
            }
        }
    __syncthreads();
    #pragma unroll
    for (int it = 0; it < 4; it++) {
        int g = it * 256 + tid;
        int ml = g >> 5;
        int ch = g & 31;
        *(uint4*)(HM_next + (size_t)(m0 + ml) * ROWB + ch * 16) =
            *(const uint4*)&sg[SWZ16(ml, ch)];
    }

    if (EMIT_HU) {
        // ---- U-GEMM: hU_next = h_next @ Ur  (A frags from sg, bf16) ----
        f32x4v au[2][4] = {};
        #pragma unroll
        for (int ksi = 0; ksi < 8; ksi++) {
            bfrag af[2], bu[4];
            #pragma unroll
            for (int i = 0; i < 2; i++) {
                int rr = i * 16 + l16;
                int q = ksi * 4 + quad;
                af[i] = *(const bfrag*)&sg[SWZ16(rr, q)];
            }
            #pragma unroll
            for (int j = 0; j < 4; j++) {
                int f = ((wv * 4 + j) * 8 + ksi) * 64 + lane;
                bu[j] = *(const bfrag*)&Ur_p[(size_t)f * 8];
            }
            #pragma unroll
            for (int i = 0; i < 2; i++)
                #pragma unroll
                for (int j = 0; j < 4; j++)
                    au[i][j] = __builtin_amdgcn_mfma_f32_16x16x32_bf16(af[i], bu[j], au[i][j], 0, 0, 0);
        }
        // write au (bf16) into sh, then coalesced fp8 pack + store
        #pragma unroll
        for (int i = 0; i < 2; i++)
            #pragma unroll
            for (int j = 0; j < 4; j++) {
                int col = wv * 64 + j * 16 + l16;
                #pragma unroll
                for (int r = 0; r < 4; r++) {
                    int rl = i * 16 + quad * 4 + r;
                    sh[SWZ16(rl, col >> 3) + (col & 7)] = f2bf_fast(au[i][j][r]);
                }
            }
        __syncthreads();
        #pragma unroll
        for (int it = 0; it < 4; it++) {
            int g = it * 256 + tid;
            int ml = g >> 5;
            int ch = g & 31;
            uint4 w = *(const uint4*)&sh[SWZ16(ml, ch)];
            float f[8] = { bfu_lo(w.x), bfu_hi(w.x), bfu_lo(w.y), bfu_hi(w.y),
                           bfu_lo(w.z), bfu_hi(w.z), bfu_lo(w.w), bfu_hi(w.w) };
            u32x2 o = pack8fp8(f);
            *(u32x2*)(HM_next + (size_t)(m0 + ml) * ROWB + 512 + ch * 8) = o;
        }
    }
}

// ---------------- fused tail: node gather + out-projection GEMM -------------
__global__ __launch_bounds__(256) void gather_out(
    const u8* __restrict__ HM, const int* __restrict__ ng,
    const int* __restrict__ fnode, const float* __restrict__ embO,
    const ush* __restrict__ Wo_p, float* __restrict__ node_vec)
{
    __shared__ __align__(16) ush sh[BMF * 256];
    int tid = threadIdx.x;
    int wv = tid >> 6, lane = tid & 63;
    int quad = lane >> 4, l16 = lane & 15;
    int n0 = blockIdx.x * BMF;

    #pragma unroll 2
    for (int it = 0; it < 4; it++) {
        int g = it * 256 + tid;
        int ml = g >> 5;
        int ch = g & 31;
        int c = ch * 8;
        int n = n0 + ml;
        float a[8] = {0,0,0,0,0,0,0,0};
        #pragma unroll
        for (int kn = 0; kn < MAXNEI; kn++) {
            int j = ng[n * MAXNEI + kn];
            s16x8 hv = *(const s16x8*)(HM + (size_t)j * ROWB + 2 * c);
            #pragma unroll
            for (int e = 0; e < 8; e++) a[e] += bf2f((ush)hv[e]);
        }
        uint4 o;
        o.x = pack2bf(a[1], a[0]); o.y = pack2bf(a[3], a[2]);
        o.z = pack2bf(a[5], a[4]); o.w = pack2bf(a[7], a[6]);
        *(uint4*)&sh[SWZ16(ml, ch)] = o;
    }
    __syncthreads();

    f32x4v acc[2][4] = {};
    #pragma unroll
    for (int ksi = 0; ksi < 8; ksi++) {
        bfrag af[2], bo[4];
        #pragma unroll
        for (int i = 0; i < 2; i++) {
            int rr = i * 16 + l16;
            int q = ksi * 4 + quad;
            af[i] = *(const bfrag*)&sh[SWZ16(rr, q)];
        }
        #pragma unroll
        for (int j = 0; j < 4; j++) {
            int f = ((wv * 4 + j) * 8 + ksi) * 64 + lane;
            bo[j] = *(const bfrag*)&Wo_p[(size_t)f * 8];
        }
        #pragma unroll
        for (int i = 0; i < 2; i++)
            #pragma unroll
            for (int j = 0; j < 4; j++)
                acc[i][j] = __builtin_amdgcn_mfma_f32_16x16x32_bf16(af[i], bo[j], acc[i][j], 0, 0, 0);
    }

    #pragma unroll
    for (int i = 0; i < 2; i++) {
        #pragma unroll
        for (int r = 0; r < 4; r++) {
            int Rn = n0 + i * 16 + quad * 4 + r;
            int v = fnode[Rn];
            #pragma unroll
            for (int j = 0; j < 4; j++) {
                int col = wv * 64 + j * 16 + l16;
                float o = acc[i][j][r] + embO[v * HD + col];
                node_vec[(size_t)Rn * HD + col] = fmaxf(o, 0.f);
            }
        }
    }
}

// ---------------- per-tree segment mean (scope_ids sorted) ------------------
__device__ __forceinline__ int lower_bound_dev(const int* a, int n, int key) {
    int lo = 0, hi = n;
    while (lo < hi) { int mid = (lo + hi) >> 1; if (a[mid] < key) lo = mid + 1; else hi = mid; }
    return lo;
}

__global__ __launch_bounds__(256) void segment_mean(
    const float* __restrict__ node_vec, const int* __restrict__ scope,
    float* __restrict__ out)
{
    int t = blockIdx.x;
    int c = threadIdx.x;
    int lo = lower_bound_dev(scope, NNODES, t);
    int hi = lower_bound_dev(scope, NNODES, t + 1);
    float acc = 0.f;
    for (int n = lo; n < hi; n++) acc += node_vec[(size_t)n * HD + c];
    int cnt = hi - lo;
    out[t * HD + c] = cnt > 0 ? acc / (float)cnt : 0.f;
}

// ---------------------------------------------------------------------------
extern "C" void kernel_launch(void* const* d_in, const int* in_sizes, int n_in,
                              void* d_out, int out_size, void* d_ws, size_t ws_size,
                              hipStream_t stream)
{
    const int*   fnode      = (const int*)d_in[0];
    const int*   fmess      = (const int*)d_in[1];
    const int*   node_graph = (const int*)d_in[2];
    const int*   mess_graph = (const int*)d_in[3];
    const int*   scope_ids  = (const int*)d_in[4];
    const float* emb        = (const float*)d_in[5];
    const float* Wz_w       = (const float*)d_in[6];
    const float* Wz_b       = (const float*)d_in[7];
    const float* Wr_w       = (const float*)d_in[8];
    const float* Ur_w       = (const float*)d_in[9];
    const float* Ur_b       = (const float*)d_in[10];
    const float* Wh_w       = (const float*)d_in[11];
    const float* Wh_b       = (const float*)d_in[12];
    const float* out_w      = (const float*)d_in[13];
    const float* out_b      = (const float*)d_in[14];

    // ---- workspace carve (~198 MiB) ----
    char* ws = (char*)d_ws;
    const size_t HMB = (size_t)NMESS * ROWB;           // 100.7 MB combined row buf
    u8* HM0 = (u8*)ws; ws += HMB;                      // ping
    u8* HM1 = (u8*)ws; ws += HMB;                      // pong
    float* embR = (float*)ws; ws += (size_t)NVOCAB * HD * 4;
    float* embZ = (float*)ws; ws += (size_t)NVOCAB * HD * 4;
    float* embH = (float*)ws; ws += (size_t)NVOCAB * HD * 4;
    float* embO = (float*)ws; ws += (size_t)NVOCAB * HD * 4;
    float* embU = (float*)ws; ws += (size_t)NVOCAB * HD * 4;
    ush* h1tab = (ush*)ws; ws += (size_t)NVOCAB * HD * 2;
    ush* Wo_p  = (ush*)ws; ws += (size_t)HD * HD * 2;
    ush* Wz_p  = (ush*)ws; ws += (size_t)HD * HD * 2;
    ush* Wh_p  = (ush*)ws; ws += (size_t)HD * HD * 2;
    ush* Ur_p  = (ush*)ws; ws += (size_t)HD * HD * 2;
    int* v_mess = (int*)ws; ws += (size_t)NMESS * 4;
    if ((size_t)(ws - (char*)d_ws) > ws_size) return;  // fail loud, not fault

    hipMemsetAsync(embR, 0, (size_t)5 * NVOCAB * HD * 4, stream);  // embR..embU
    prep_tables_sk<<<dim3(NVOCAB / 4, 4), 256, 0, stream>>>(
        emb, Wz_w, Wz_b, Wr_w, Ur_b, Wh_w, Wh_b, out_w, out_b,
        embR, embZ, embH, embO);
    h1fill<<<NVOCAB, 256, 0, stream>>>(embZ, embH, h1tab);
    h1u_sk<<<dim3(NVOCAB / 4, 4), 256, 0, stream>>>(h1tab, Ur_w, embU);
    prep_wt<<<HD * HD / 256, 256, 0, stream>>>(Ur_w, Wz_w, Wh_w, out_w,
                                               Wo_p, Wz_p, Wh_p, Ur_p);
    prep_vmess<<<NMESS / 256, 256, 0, stream>>>(fnode, fmess, v_mess);
    fill_h1<<<NMESS * 32 / 256, 256, 0, stream>>>(h1tab, embU, v_mess, HM0);

    u8* hc = HM0; u8* hn = HM1;
    for (int d = 1; d < 5; d++) {
        fused_step<1><<<NMESS / BMF, 256, 0, stream>>>(hc, mess_graph, v_mess,
                                                       embR, embZ, embH,
                                                       Wz_p, Wh_p, Ur_p, hn);
        u8* t = hc; hc = hn; hn = t;
    }
    fused_step<0><<<NMESS / BMF, 256, 0, stream>>>(hc, mess_graph, v_mess,
                                                   embR, embZ, embH,
                                                   Wz_p, Wh_p, Ur_p, hn);
    hc = hn;  // final HM (h part valid); the other buffer is free

    float* node_vec = (float*)(hc == HM0 ? HM1 : HM0);  // 67 MB < 100.7 MB ✓
    gather_out<<<NNODES / BMF, 256, 0, stream>>>(hc, node_graph, fnode, embO,
                                                 Wo_p, node_vec);
    segment_mean<<<NTREES, 256, 0, stream>>>(node_vec, scope_ids, (float*)d_out);
}

// Round 12
// 1180.659 us; speedup vs baseline: 1.4514x; 1.4514x over previous
//
#include <hip/hip_runtime.h>

// JTNN encoder, MI355X.
//  - hU = h @ Ur_w once per row, gathered (5x FLOP cut vs h_nei@Ur)
//  - h bf16 (fp8-h FAILED accuracy R7); hU fp8 e4m3 (validated safe R6)
//  - h + hU interleaved in ONE 768 B/row buffer HM (single random fetch/neighbor)
//  - R10: NT stores disproved write-pollution (reverted). R11: LDS 32 KiB +
//    launch_bounds(256,5) forced VGPR 64->48 -> scratch spills (+535 MB traffic,
//    1.6x slower). R12: keep 32 KiB swizzled LDS (5 blocks/CU) but bounds
//    (256,4) so the allocator keeps 64 VGPR -- occupancy comes from LDS fit,
//    not a register cap.
//  - x-side projections folded into per-VOCAB tables (780 rows, L2-resident)
//  - depth-0 closed form: h1 = sigma(embZ[v]) * tanh(embH[v]); hU1 = (h1tab@Ur)[v]
//  - fused_step: gather + Z/P GEMM + GRU update + U-GEMM in ONE kernel
//  - gather_out: node-side gather + out-projection GEMM fused

#define HD 256
#define NNODES 65536
#define NMESS 131072
#define NVOCAB 780
#define NTREES 2048
#define MAXNEI 5
#define BMF 32
#define ROWB 768    // HM row bytes: 512 h-bf16 + 256 u-fp8

// XOR-swizzled LDS addressing: element (row, col) chunk c=col>>3 lives at
// row*256 + ((c ^ (row&7))<<3) + (col&7).  <=2-way bank aliasing (free).
#define SWZ16(row, chunk) ((row) * 256 + ((((chunk) ^ ((row) & 7))) << 3))

typedef short bfrag __attribute__((ext_vector_type(8)));   // 8 bf16 in 4 VGPRs
typedef short s16x8 __attribute__((ext_vector_type(8)));
typedef float f32x4v __attribute__((ext_vector_type(4)));
typedef float f32x2 __attribute__((ext_vector_type(2)));
typedef unsigned int u32x2 __attribute__((ext_vector_type(2)));
typedef unsigned short ush;
typedef unsigned char u8;

__device__ __forceinline__ float bf2f(ush u) {
    union { unsigned int u; float f; } v; v.u = ((unsigned int)u) << 16; return v.f;
}
__device__ __forceinline__ float bfu_lo(unsigned int w) {
    union { unsigned int u; float f; } v; v.u = w << 16; return v.f;
}
__device__ __forceinline__ float bfu_hi(unsigned int w) {
    union { unsigned int u; float f; } v; v.u = w & 0xffff0000u; return v.f;
}
__device__ __forceinline__ ush f2bf_fast(float f) {
    union { float f; unsigned int u; } v; v.f = f;
    return (ush)((v.u + 0x8000u) >> 16);
}
__device__ __forceinline__ unsigned int pack2bf(float hi, float lo) {
    union { float f; unsigned int u; } a, b; a.f = hi; b.f = lo;
    return __builtin_amdgcn_perm(a.u + 0x8000u, b.u + 0x8000u, 0x07060302u);
}
__device__ __forceinline__ float sigm(float x) {
    return __builtin_amdgcn_rcpf(1.f + __expf(-x));
}
__device__ __forceinline__ float tanh_fast(float x) {
    return 1.f - 2.f * __builtin_amdgcn_rcpf(__expf(2.f * x) + 1.f);
}
// 8 f32 -> 8 fp8 e4m3 packed in u32x2
__device__ __forceinline__ u32x2 pack8fp8(const float* f) {
    int lo = __builtin_amdgcn_cvt_pk_fp8_f32(f[0], f[1], 0, 0);
    lo = __builtin_amdgcn_cvt_pk_fp8_f32(f[2], f[3], lo, 1);
    int hi = __builtin_amdgcn_cvt_pk_fp8_f32(f[4], f[5], 0, 0);
    hi = __builtin_amdgcn_cvt_pk_fp8_f32(f[6], f[7], hi, 1);
    u32x2 o; o.x = (unsigned int)lo; o.y = (unsigned int)hi; return o;
}
// 8 fp8 e4m3 (u32x2) -> 8 f32
__device__ __forceinline__ void fp8x8_to_f32(u32x2 v, float* f) {
    f32x2 a = __builtin_amdgcn_cvt_pk_f32_fp8((int)v.x, false);
    f32x2 b = __builtin_amdgcn_cvt_pk_f32_fp8((int)v.x, true);
    f32x2 c = __builtin_amdgcn_cvt_pk_f32_fp8((int)v.y, false);
    f32x2 d = __builtin_amdgcn_cvt_pk_f32_fp8((int)v.y, true);
    f[0] = a.x; f[1] = a.y; f[2] = b.x; f[3] = b.y;
    f[4] = c.x; f[5] = c.y; f[6] = d.x; f[7] = d.y;
}

// ---------------- prep: vocab tables, split-k over 4 blocks (atomicAdd) -----
__global__ __launch_bounds__(256) void prep_tables_sk(
    const float* __restrict__ emb,
    const float* __restrict__ Wz_w, const float* __restrict__ Wz_b,
    const float* __restrict__ Wr_w, const float* __restrict__ Ur_b,
    const float* __restrict__ Wh_w, const float* __restrict__ Wh_b,
    const float* __restrict__ out_w, const float* __restrict__ out_b,
    float* __restrict__ embR, float* __restrict__ embZ,
    float* __restrict__ embH, float* __restrict__ embO)
{
    __shared__ __align__(16) float e[4][64];
    int t = threadIdx.x;
    int b0 = blockIdx.x * 4;
    int k0 = blockIdx.y * 64;
    e[t >> 6][t & 63] = emb[(b0 + (t >> 6)) * HD + k0 + (t & 63)];
    __syncthreads();
    float aR[4] = {0,0,0,0}, aZ[4] = {0,0,0,0}, aH[4] = {0,0,0,0}, aO[4] = {0,0,0,0};
    for (int kk = 0; kk < 64; kk++) {
        int k = k0 + kk;
        float wr = Wr_w[k * HD + t];
        float wz = Wz_w[k * HD + t];
        float wh = Wh_w[k * HD + t];
        float wo = out_w[k * HD + t];
        #pragma unroll
        for (int r = 0; r < 4; r++) {
            float ev = e[r][kk];
            aR[r] += ev * wr; aZ[r] += ev * wz; aH[r] += ev * wh; aO[r] += ev * wo;
        }
    }
    if (blockIdx.y == 0) {
        float br = Ur_b[t], bz = Wz_b[t], bh = Wh_b[t], bo = out_b[t];
        #pragma unroll
        for (int r = 0; r < 4; r++) { aR[r] += br; aZ[r] += bz; aH[r] += bh; aO[r] += bo; }
    }
    #pragma unroll
    for (int r = 0; r < 4; r++) {
        atomicAdd(&embR[(b0 + r) * HD + t], aR[r]);
        atomicAdd(&embZ[(b0 + r) * HD + t], aZ[r]);
        atomicAdd(&embH[(b0 + r) * HD + t], aH[r]);
        atomicAdd(&embO[(b0 + r) * HD + t], aO[r]);
    }
}

// h1tab[v] = sigmoid(embZ[v]) * tanh(embH[v])   (depth-0 closed form)
__global__ __launch_bounds__(256) void h1fill(
    const float* __restrict__ embZ, const float* __restrict__ embH,
    ush* __restrict__ h1tab)
{
    int i = blockIdx.x * HD + threadIdx.x;
    h1tab[i] = f2bf_fast(sigm(embZ[i]) * tanh_fast(embH[i]));
}

// embU[v] = h1tab[v] @ Ur_w  (780x256 rows, split-k atomic)
__global__ __launch_bounds__(256) void h1u_sk(
    const ush* __restrict__ h1tab, const float* __restrict__ Ur_w,
    float* __restrict__ embU)
{
    __shared__ __align__(16) float e[4][64];
    int t = threadIdx.x;
    int b0 = blockIdx.x * 4;
    int k0 = blockIdx.y * 64;
    e[t >> 6][t & 63] = bf2f(h1tab[(b0 + (t >> 6)) * HD + k0 + (t & 63)]);
    __syncthreads();
    float aU[4] = {0,0,0,0};
    for (int kk = 0; kk < 64; kk++) {
        float w = Ur_w[(k0 + kk) * HD + t];
        #pragma unroll
        for (int r = 0; r < 4; r++) aU[r] += e[r][kk] * w;
    }
    #pragma unroll
    for (int r = 0; r < 4; r++) atomicAdd(&embU[(b0 + r) * HD + t], aU[r]);
}

// weights: fragment-packed (Wz_p, Wh_p, Ur_p, Wo_p).
__global__ __launch_bounds__(256) void prep_wt(
    const float* __restrict__ Ur_w, const float* __restrict__ Wz_w,
    const float* __restrict__ Wh_w, const float* __restrict__ out_w,
    ush* __restrict__ Wo_p,
    ush* __restrict__ Wz_p, ush* __restrict__ Wh_p, ush* __restrict__ Ur_p)
{
    int idx = blockIdx.x * 256 + threadIdx.x;   // n*256 + k
    int n = idx >> 8, k = idx & 255;
    int paddr = ((((n >> 4) * 8 + (k >> 5)) * 64 + ((k >> 3) & 3) * 16 + (n & 15)) << 3) + (k & 7);
    Wo_p[paddr] = f2bf_fast(out_w[(HD + k) * HD + n]);
    Wz_p[paddr] = f2bf_fast(Wz_w[(HD + k) * HD + n]);
    Wh_p[paddr] = f2bf_fast(Wh_w[(HD + k) * HD + n]);
    Ur_p[paddr] = f2bf_fast(Ur_w[k * HD + n]);
}

__global__ __launch_bounds__(256) void prep_vmess(
    const int* __restrict__ fnode, const int* __restrict__ fmess,
    int* __restrict__ v_mess)
{
    int m = blockIdx.x * 256 + threadIdx.x;
    v_mess[m] = fnode[fmess[m]];
}

// depth-0 fill: HM row m = [h1tab[v] bf16 | fp8(embU[v])]; row 0 = 0
__global__ __launch_bounds__(256) void fill_h1(
    const ush* __restrict__ h1tab, const float* __restrict__ embU,
    const int* __restrict__ v_mess, u8* __restrict__ HM)
{
    int t = blockIdx.x * 256 + threadIdx.x;
    int m = t >> 5;
    int c = (t & 31) * 8;          // elem offset 0..248
    int v = v_mess[m];
    s16x8 o = *(const s16x8*)&h1tab[v * HD + c];
    float u[8];
    *(float4*)&u[0] = *(const float4*)&embU[v * HD + c];
    *(float4*)&u[4] = *(const float4*)&embU[v * HD + c + 4];
    u32x2 up = pack8fp8(u);
    if (m == 0) { o = (s16x8){0,0,0,0,0,0,0,0}; up.x = up.y = 0; }
    u8* row = HM + (size_t)m * ROWB;
    *(s16x8*)(row + 2 * c) = o;
    *(u32x2*)(row + 512 + c) = up;
}

// ---------------- fused step: gather + Z/P GEMM + GRU + U-GEMM --------------
// 32 messages/block, 256 threads (4 waves), LDS exactly 32 KiB -> LDS permits
// 5 blocks/CU; launch_bounds floor kept at 4 so the allocator stays at ~64
// VGPR (R11: forcing 5 caused 48-VGPR spills, +535 MB scratch traffic).
template<int EMIT_HU>
__global__ __launch_bounds__(256, 4) void fused_step(
    const u8* __restrict__ HM, const int* __restrict__ mg,
    const int* __restrict__ v_mess,
    const float* __restrict__ embR, const float* __restrict__ embZ,
    const float* __restrict__ embH,
    const ush* __restrict__ Wz_p, const ush* __restrict__ Wh_p,
    const ush* __restrict__ Ur_p,
    u8* __restrict__ HM_next)
{
    __shared__ __align__(16) ush sh[BMF * 256];   // sum_h tile  (16 KiB, swizzled)
    __shared__ __align__(16) ush sg[BMF * 256];   // sum_gh -> h_next tile
    int tid = threadIdx.x;
    int wv = tid >> 6, lane = tid & 63;
    int quad = lane >> 4, l16 = lane & 15;
    int m0 = blockIdx.x * BMF;

    // ---- phase 1: gather + r-gate into LDS (one 768B row fetch/neighbor) ----
    #pragma unroll 2
    for (int it = 0; it < 4; it++) {
        int g = it * 256 + tid;
        int ml = g >> 5;               // 0..31
        int ch = g & 31;               // chunk 0..31; col c = ch*8
        int c = ch * 8;
        int m = m0 + ml;
        int v = v_mess[m];
        int jj[MAXNEI];
        #pragma unroll
        for (int kn = 0; kn < MAXNEI; kn++) jj[kn] = mg[m * MAXNEI + kn];
        float rb[8];
        *(float4*)&rb[0] = *(const float4*)&embR[v * HD + c];
        *(float4*)&rb[4] = *(const float4*)&embR[v * HD + c + 4];
        float ah[8] = {0,0,0,0,0,0,0,0};
        float ag[8] = {0,0,0,0,0,0,0,0};
        #pragma unroll
        for (int kn = 0; kn < MAXNEI; kn++) {
            const u8* row = HM + (size_t)jj[kn] * ROWB;
            s16x8 hv = *(const s16x8*)(row + 2 * c);
            u32x2 uv8 = *(const u32x2*)(row + 512 + c);
            float uf[8];
            fp8x8_to_f32(uv8, uf);
            #pragma unroll
            for (int e = 0; e < 8; e++) {
                float hf = bf2f((ush)hv[e]);
                ah[e] += hf;
                ag[e] += sigm(rb[e] + uf[e]) * hf;
            }
        }
        uint4 oh, og;
        oh.x = pack2bf(ah[1], ah[0]); oh.y = pack2bf(ah[3], ah[2]);
        oh.z = pack2bf(ah[5], ah[4]); oh.w = pack2bf(ah[7], ah[6]);
        og.x = pack2bf(ag[1], ag[0]); og.y = pack2bf(ag[3], ag[2]);
        og.z = pack2bf(ag[5], ag[4]); og.w = pack2bf(ag[7], ag[6]);
        *(uint4*)&sh[SWZ16(ml, ch)] = oh;
        *(uint4*)&sg[SWZ16(ml, ch)] = og;
    }
    __syncthreads();

    // ---- phase 2: Z = sum_h @ Wz2, P = sum_gh @ Wh2 (B frags from global) ----
    f32x4v az[2][4] = {}, ap[2][4] = {};
    #pragma unroll
    for (int ksi = 0; ksi < 8; ksi++) {
        bfrag ahf[2], agf[2], bz[4], bh[4];
        #pragma unroll
        for (int i = 0; i < 2; i++) {
            int rr = i * 16 + l16;
            int q = ksi * 4 + quad;
            ahf[i] = *(const bfrag*)&sh[SWZ16(rr, q)];
            agf[i] = *(const bfrag*)&sg[SWZ16(rr, q)];
        }
        #pragma unroll
        for (int j = 0; j < 4; j++) {
            int f = ((wv * 4 + j) * 8 + ksi) * 64 + lane;
            bz[j] = *(const bfrag*)&Wz_p[(size_t)f * 8];
            bh[j] = *(const bfrag*)&Wh_p[(size_t)f * 8];
        }
        #pragma unroll
        for (int i = 0; i < 2; i++)
            #pragma unroll
            for (int j = 0; j < 4; j++) {
                az[i][j] = __builtin_amdgcn_mfma_f32_16x16x32_bf16(ahf[i], bz[j], az[i][j], 0, 0, 0);
                ap[i][j] = __builtin_amdgcn_mfma_f32_16x16x32_bf16(agf[i], bh[j], ap[i][j], 0, 0, 0);
            }
    }

    // ---- GRU combine: az[i][j][r] <- h_next value (reuse regs) ----
    #pragma unroll
    for (int i = 0; i < 2; i++) {
        #pragma unroll
        for (int r = 0; r < 4; r++) {
            int rl = i * 16 + quad * 4 + r;
            int Rg = m0 + rl;
            int v = v_mess[Rg];
            #pragma unroll
            for (int j = 0; j < 4; j++) {
                int col = wv * 64 + j * 16 + l16;
                float z = sigm(az[i][j][r] + embZ[v * HD + col]);
                float pre = tanh_fast(ap[i][j][r] + embH[v * HD + col]);
                float shv = bf2f(sh[SWZ16(rl, col >> 3) + (col & 7)]);
                float hn = (1.f - z) * shv + z * pre;
                if (Rg == 0) hn = 0.f;
                az[i][j][r] = hn;
            }
        }
    }
    __syncthreads();   // all sh/sg reads done

    // ---- h_next tile into sg (LDS), then coalesced bf16 global write ----
    #pragma unroll
    for (int i = 0; i < 2; i++)
        #pragma unroll
        for (int j = 0; j < 4; j++) {
            int col = wv * 64 + j * 16 + l16;
            #pragma unroll
            for (int r = 0; r < 4; r++) {
                int rl = i * 16 + quad * 4 + r;
                sg[SWZ16(rl, col >> 3) + (col & 7)] = f2bf_fast(az[i][j][r]);
            }
        }
    __syncthreads();
    #pragma unroll
    for (int it = 0; it < 4; it++) {
        int g = it * 256 + tid;
        int ml = g >> 5;
        int ch = g & 31;
        *(uint4*)(HM_next + (size_t)(m0 + ml) * ROWB + ch * 16) =
            *(const uint4*)&sg[SWZ16(ml, ch)];
    }

    if (EMIT_HU) {
        // ---- U-GEMM: hU_next = h_next @ Ur  (A frags from sg, bf16) ----
        f32x4v au[2][4] = {};
        #pragma unroll
        for (int ksi = 0; ksi < 8; ksi++) {
            bfrag af[2], bu[4];
            #pragma unroll
            for (int i = 0; i < 2; i++) {
                int rr = i * 16 + l16;
                int q = ksi * 4 + quad;
                af[i] = *(const bfrag*)&sg[SWZ16(rr, q)];
            }
            #pragma unroll
            for (int j = 0; j < 4; j++) {
                int f = ((wv * 4 + j) * 8 + ksi) * 64 + lane;
                bu[j] = *(const bfrag*)&Ur_p[(size_t)f * 8];
            }
            #pragma unroll
            for (int i = 0; i < 2; i++)
                #pragma unroll
                for (int j = 0; j < 4; j++)
                    au[i][j] = __builtin_amdgcn_mfma_f32_16x16x32_bf16(af[i], bu[j], au[i][j], 0, 0, 0);
        }
        // write au (bf16) into sh, then coalesced fp8 pack + store
        #pragma unroll
        for (int i = 0; i < 2; i++)
            #pragma unroll
            for (int j = 0; j < 4; j++) {
                int col = wv * 64 + j * 16 + l16;
                #pragma unroll
                for (int r = 0; r < 4; r++) {
                    int rl = i * 16 + quad * 4 + r;
                    sh[SWZ16(rl, col >> 3) + (col & 7)] = f2bf_fast(au[i][j][r]);
                }
            }
        __syncthreads();
        #pragma unroll
        for (int it = 0; it < 4; it++) {
            int g = it * 256 + tid;
            int ml = g >> 5;
            int ch = g & 31;
            uint4 w = *(const uint4*)&sh[SWZ16(ml, ch)];
            float f[8] = { bfu_lo(w.x), bfu_hi(w.x), bfu_lo(w.y), bfu_hi(w.y),
                           bfu_lo(w.z), bfu_hi(w.z), bfu_lo(w.w), bfu_hi(w.w) };
            u32x2 o = pack8fp8(f);
            *(u32x2*)(HM_next + (size_t)(m0 + ml) * ROWB + 512 + ch * 8) = o;
        }
    }
}

// ---------------- fused tail: node gather + out-projection GEMM -------------
__global__ __launch_bounds__(256) void gather_out(
    const u8* __restrict__ HM, const int* __restrict__ ng,
    const int* __restrict__ fnode, const float* __restrict__ embO,
    const ush* __restrict__ Wo_p, float* __restrict__ node_vec)
{
    __shared__ __align__(16) ush sh[BMF * 256];
    int tid = threadIdx.x;
    int wv = tid >> 6, lane = tid & 63;
    int quad = lane >> 4, l16 = lane & 15;
    int n0 = blockIdx.x * BMF;

    #pragma unroll 2
    for (int it = 0; it < 4; it++) {
        int g = it * 256 + tid;
        int ml = g >> 5;
        int ch = g & 31;
        int c = ch * 8;
        int n = n0 + ml;
        float a[8] = {0,0,0,0,0,0,0,0};
        #pragma unroll
        for (int kn = 0; kn < MAXNEI; kn++) {
            int j = ng[n * MAXNEI + kn];
            s16x8 hv = *(const s16x8*)(HM + (size_t)j * ROWB + 2 * c);
            #pragma unroll
            for (int e = 0; e < 8; e++) a[e] += bf2f((ush)hv[e]);
        }
        uint4 o;
        o.x = pack2bf(a[1], a[0]); o.y = pack2bf(a[3], a[2]);
        o.z = pack2bf(a[5], a[4]); o.w = pack2bf(a[7], a[6]);
        *(uint4*)&sh[SWZ16(ml, ch)] = o;
    }
    __syncthreads();

    f32x4v acc[2][4] = {};
    #pragma unroll
    for (int ksi = 0; ksi < 8; ksi++) {
        bfrag af[2], bo[4];
        #pragma unroll
        for (int i = 0; i < 2; i++) {
            int rr = i * 16 + l16;
            int q = ksi * 4 + quad;
            af[i] = *(const bfrag*)&sh[SWZ16(rr, q)];
        }
        #pragma unroll
        for (int j = 0; j < 4; j++) {
            int f = ((wv * 4 + j) * 8 + ksi) * 64 + lane;
            bo[j] = *(const bfrag*)&Wo_p[(size_t)f * 8];
        }
        #pragma unroll
        for (int i = 0; i < 2; i++)
            #pragma unroll
            for (int j = 0; j < 4; j++)
                acc[i][j] = __builtin_amdgcn_mfma_f32_16x16x32_bf16(af[i], bo[j], acc[i][j], 0, 0, 0);
    }

    #pragma unroll
    for (int i = 0; i < 2; i++) {
        #pragma unroll
        for (int r = 0; r < 4; r++) {
            int Rn = n0 + i * 16 + quad * 4 + r;
            int v = fnode[Rn];
            #pragma unroll
            for (int j = 0; j < 4; j++) {
                int col = wv * 64 + j * 16 + l16;
                float o = acc[i][j][r] + embO[v * HD + col];
                node_vec[(size_t)Rn * HD + col] = fmaxf(o, 0.f);
            }
        }
    }
}

// ---------------- per-tree segment mean (scope_ids sorted) ------------------
__device__ __forceinline__ int lower_bound_dev(const int* a, int n, int key) {
    int lo = 0, hi = n;
    while (lo < hi) { int mid = (lo + hi) >> 1; if (a[mid] < key) lo = mid + 1; else hi = mid; }
    return lo;
}

__global__ __launch_bounds__(256) void segment_mean(
    const float* __restrict__ node_vec, const int* __restrict__ scope,
    float* __restrict__ out)
{
    int t = blockIdx.x;
    int c = threadIdx.x;
    int lo = lower_bound_dev(scope, NNODES, t);
    int hi = lower_bound_dev(scope, NNODES, t + 1);
    float acc = 0.f;
    for (int n = lo; n < hi; n++) acc += node_vec[(size_t)n * HD + c];
    int cnt = hi - lo;
    out[t * HD + c] = cnt > 0 ? acc / (float)cnt : 0.f;
}

// ---------------------------------------------------------------------------
extern "C" void kernel_launch(void* const* d_in, const int* in_sizes, int n_in,
                              void* d_out, int out_size, void* d_ws, size_t ws_size,
                              hipStream_t stream)
{
    const int*   fnode      = (const int*)d_in[0];
    const int*   fmess      = (const int*)d_in[1];
    const int*   node_graph = (const int*)d_in[2];
    const int*   mess_graph = (const int*)d_in[3];
    const int*   scope_ids  = (const int*)d_in[4];
    const float* emb        = (const float*)d_in[5];
    const float* Wz_w       = (const float*)d_in[6];
    const float* Wz_b       = (const float*)d_in[7];
    const float* Wr_w       = (const float*)d_in[8];
    const float* Ur_w       = (const float*)d_in[9];
    const float* Ur_b       = (const float*)d_in[10];
    const float* Wh_w       = (const float*)d_in[11];
    const float* Wh_b       = (const float*)d_in[12];
    const float* out_w      = (const float*)d_in[13];
    const float* out_b      = (const float*)d_in[14];

    // ---- workspace carve (~198 MiB) ----
    char* ws = (char*)d_ws;
    const size_t HMB = (size_t)NMESS * ROWB;           // 100.7 MB combined row buf
    u8* HM0 = (u8*)ws; ws += HMB;                      // ping
    u8* HM1 = (u8*)ws; ws += HMB;                      // pong
    float* embR = (float*)ws; ws += (size_t)NVOCAB * HD * 4;
    float* embZ = (float*)ws; ws += (size_t)NVOCAB * HD * 4;
    float* embH = (float*)ws; ws += (size_t)NVOCAB * HD * 4;
    float* embO = (float*)ws; ws += (size_t)NVOCAB * HD * 4;
    float* embU = (float*)ws; ws += (size_t)NVOCAB * HD * 4;
    ush* h1tab = (ush*)ws; ws += (size_t)NVOCAB * HD * 2;
    ush* Wo_p  = (ush*)ws; ws += (size_t)HD * HD * 2;
    ush* Wz_p  = (ush*)ws; ws += (size_t)HD * HD * 2;
    ush* Wh_p  = (ush*)ws; ws += (size_t)HD * HD * 2;
    ush* Ur_p  = (ush*)ws; ws += (size_t)HD * HD * 2;
    int* v_mess = (int*)ws; ws += (size_t)NMESS * 4;
    if ((size_t)(ws - (char*)d_ws) > ws_size) return;  // fail loud, not fault

    hipMemsetAsync(embR, 0, (size_t)5 * NVOCAB * HD * 4, stream);  // embR..embU
    prep_tables_sk<<<dim3(NVOCAB / 4, 4), 256, 0, stream>>>(
        emb, Wz_w, Wz_b, Wr_w, Ur_b, Wh_w, Wh_b, out_w, out_b,
        embR, embZ, embH, embO);
    h1fill<<<NVOCAB, 256, 0, stream>>>(embZ, embH, h1tab);
    h1u_sk<<<dim3(NVOCAB / 4, 4), 256, 0, stream>>>(h1tab, Ur_w, embU);
    prep_wt<<<HD * HD / 256, 256, 0, stream>>>(Ur_w, Wz_w, Wh_w, out_w,
                                               Wo_p, Wz_p, Wh_p, Ur_p);
    prep_vmess<<<NMESS / 256, 256, 0, stream>>>(fnode, fmess, v_mess);
    fill_h1<<<NMESS * 32 / 256, 256, 0, stream>>>(h1tab, embU, v_mess, HM0);

    u8* hc = HM0; u8* hn = HM1;
    for (int d = 1; d < 5; d++) {
        fused_step<1><<<NMESS / BMF, 256, 0, stream>>>(hc, mess_graph, v_mess,
                                                       embR, embZ, embH,
                                                       Wz_p, Wh_p, Ur_p, hn);
        u8* t = hc; hc = hn; hn = t;
    }
    fused_step<0><<<NMESS / BMF, 256, 0, stream>>>(hc, mess_graph, v_mess,
                                                   embR, embZ, embH,
                                                   Wz_p, Wh_p, Ur_p, hn);
    hc = hn;  // final HM (h part valid); the other buffer is free

    float* node_vec = (float*)(hc == HM0 ? HM1 : HM0);  // 67 MB < 100.7 MB ✓
    gather_out<<<NNODES / BMF, 256, 0, stream>>>(hc, node_graph, fnode, embO,
                                                 Wo_p, node_vec);
    segment_mean<<<NTREES, 256, 0, stream>>>(node_vec, scope_ids, (float*)d_out);
}

// Round 13
// 1035.486 us; speedup vs baseline: 1.6549x; 1.1402x over previous
//
#include <hip/hip_runtime.h>

// JTNN encoder, MI355X.
//  - hU = h @ Ur_w once per row, gathered (5x FLOP cut vs h_nei@Ur)
//  - h bf16 (fp8-h FAILED accuracy R7); hU fp8 e4m3 (validated safe R6)
//  - h + hU interleaved in ONE 768 B/row buffer HM (single random fetch/neighbor)
//  - R10 NT stores: disproved write-pollution (reverted). R11 reg-cap: spills.
//    R12 LDS-shrink+swizzle: occupancy unchanged, traffic up (reverted).
//    R9 config is champion: LDF=264 pad, bounds(256,4), plain stores.
//  - R13: depth-1 gather reads the VOCAB TABLES (h1tab/embU8, L2-resident)
//    via v_mess[j] instead of the 100 MB HM buffer; fill_h1 eliminated.
//  - x-side projections folded into per-VOCAB tables (780 rows, L2-resident)
//  - depth-0 closed form: h1 = sigma(embZ[v]) * tanh(embH[v]); hU1 = (h1tab@Ur)[v]
//  - fused_step: gather + Z/P GEMM + GRU update + U-GEMM in ONE kernel
//  - gather_out: node-side gather + out-projection GEMM fused

#define HD 256
#define NNODES 65536
#define NMESS 131072
#define NVOCAB 780
#define NTREES 2048
#define MAXNEI 5
#define BMF 32
#define LDF 264     // padded LDS stride (shorts)
#define ROWB 768    // HM row bytes: 512 h-bf16 + 256 u-fp8

typedef short bfrag __attribute__((ext_vector_type(8)));   // 8 bf16 in 4 VGPRs
typedef short s16x8 __attribute__((ext_vector_type(8)));
typedef float f32x4v __attribute__((ext_vector_type(4)));
typedef float f32x2 __attribute__((ext_vector_type(2)));
typedef unsigned int u32x2 __attribute__((ext_vector_type(2)));
typedef unsigned short ush;
typedef unsigned char u8;

__device__ __forceinline__ float bf2f(ush u) {
    union { unsigned int u; float f; } v; v.u = ((unsigned int)u) << 16; return v.f;
}
__device__ __forceinline__ float bfu_lo(unsigned int w) {
    union { unsigned int u; float f; } v; v.u = w << 16; return v.f;
}
__device__ __forceinline__ float bfu_hi(unsigned int w) {
    union { unsigned int u; float f; } v; v.u = w & 0xffff0000u; return v.f;
}
__device__ __forceinline__ ush f2bf_fast(float f) {
    union { float f; unsigned int u; } v; v.f = f;
    return (ush)((v.u + 0x8000u) >> 16);
}
__device__ __forceinline__ unsigned int pack2bf(float hi, float lo) {
    union { float f; unsigned int u; } a, b; a.f = hi; b.f = lo;
    return __builtin_amdgcn_perm(a.u + 0x8000u, b.u + 0x8000u, 0x07060302u);
}
__device__ __forceinline__ float sigm(float x) {
    return __builtin_amdgcn_rcpf(1.f + __expf(-x));
}
__device__ __forceinline__ float tanh_fast(float x) {
    return 1.f - 2.f * __builtin_amdgcn_rcpf(__expf(2.f * x) + 1.f);
}
// 8 f32 -> 8 fp8 e4m3 packed in u32x2
__device__ __forceinline__ u32x2 pack8fp8(const float* f) {
    int lo = __builtin_amdgcn_cvt_pk_fp8_f32(f[0], f[1], 0, 0);
    lo = __builtin_amdgcn_cvt_pk_fp8_f32(f[2], f[3], lo, 1);
    int hi = __builtin_amdgcn_cvt_pk_fp8_f32(f[4], f[5], 0, 0);
    hi = __builtin_amdgcn_cvt_pk_fp8_f32(f[6], f[7], hi, 1);
    u32x2 o; o.x = (unsigned int)lo; o.y = (unsigned int)hi; return o;
}
// 8 fp8 e4m3 (u32x2) -> 8 f32
__device__ __forceinline__ void fp8x8_to_f32(u32x2 v, float* f) {
    f32x2 a = __builtin_amdgcn_cvt_pk_f32_fp8((int)v.x, false);
    f32x2 b = __builtin_amdgcn_cvt_pk_f32_fp8((int)v.x, true);
    f32x2 c = __builtin_amdgcn_cvt_pk_f32_fp8((int)v.y, false);
    f32x2 d = __builtin_amdgcn_cvt_pk_f32_fp8((int)v.y, true);
    f[0] = a.x; f[1] = a.y; f[2] = b.x; f[3] = b.y;
    f[4] = c.x; f[5] = c.y; f[6] = d.x; f[7] = d.y;
}

// ---------------- prep: vocab tables, split-k over 4 blocks (atomicAdd) -----
__global__ __launch_bounds__(256) void prep_tables_sk(
    const float* __restrict__ emb,
    const float* __restrict__ Wz_w, const float* __restrict__ Wz_b,
    const float* __restrict__ Wr_w, const float* __restrict__ Ur_b,
    const float* __restrict__ Wh_w, const float* __restrict__ Wh_b,
    const float* __restrict__ out_w, const float* __restrict__ out_b,
    float* __restrict__ embR, float* __restrict__ embZ,
    float* __restrict__ embH, float* __restrict__ embO)
{
    __shared__ __align__(16) float e[4][64];
    int t = threadIdx.x;
    int b0 = blockIdx.x * 4;
    int k0 = blockIdx.y * 64;
    e[t >> 6][t & 63] = emb[(b0 + (t >> 6)) * HD + k0 + (t & 63)];
    __syncthreads();
    float aR[4] = {0,0,0,0}, aZ[4] = {0,0,0,0}, aH[4] = {0,0,0,0}, aO[4] = {0,0,0,0};
    for (int kk = 0; kk < 64; kk++) {
        int k = k0 + kk;
        float wr = Wr_w[k * HD + t];
        float wz = Wz_w[k * HD + t];
        float wh = Wh_w[k * HD + t];
        float wo = out_w[k * HD + t];
        #pragma unroll
        for (int r = 0; r < 4; r++) {
            float ev = e[r][kk];
            aR[r] += ev * wr; aZ[r] += ev * wz; aH[r] += ev * wh; aO[r] += ev * wo;
        }
    }
    if (blockIdx.y == 0) {
        float br = Ur_b[t], bz = Wz_b[t], bh = Wh_b[t], bo = out_b[t];
        #pragma unroll
        for (int r = 0; r < 4; r++) { aR[r] += br; aZ[r] += bz; aH[r] += bh; aO[r] += bo; }
    }
    #pragma unroll
    for (int r = 0; r < 4; r++) {
        atomicAdd(&embR[(b0 + r) * HD + t], aR[r]);
        atomicAdd(&embZ[(b0 + r) * HD + t], aZ[r]);
        atomicAdd(&embH[(b0 + r) * HD + t], aH[r]);
        atomicAdd(&embO[(b0 + r) * HD + t], aO[r]);
    }
}

// h1tab[v] = sigmoid(embZ[v]) * tanh(embH[v])   (depth-0 closed form)
__global__ __launch_bounds__(256) void h1fill(
    const float* __restrict__ embZ, const float* __restrict__ embH,
    ush* __restrict__ h1tab)
{
    int i = blockIdx.x * HD + threadIdx.x;
    h1tab[i] = f2bf_fast(sigm(embZ[i]) * tanh_fast(embH[i]));
}

// embU[v] = h1tab[v] @ Ur_w  (780x256 rows, split-k atomic)
__global__ __launch_bounds__(256) void h1u_sk(
    const ush* __restrict__ h1tab, const float* __restrict__ Ur_w,
    float* __restrict__ embU)
{
    __shared__ __align__(16) float e[4][64];
    int t = threadIdx.x;
    int b0 = blockIdx.x * 4;
    int k0 = blockIdx.y * 64;
    e[t >> 6][t & 63] = bf2f(h1tab[(b0 + (t >> 6)) * HD + k0 + (t & 63)]);
    __syncthreads();
    float aU[4] = {0,0,0,0};
    for (int kk = 0; kk < 64; kk++) {
        float w = Ur_w[(k0 + kk) * HD + t];
        #pragma unroll
        for (int r = 0; r < 4; r++) aU[r] += e[r][kk] * w;
    }
    #pragma unroll
    for (int r = 0; r < 4; r++) atomicAdd(&embU[(b0 + r) * HD + t], aU[r]);
}

// pack embU (f32) -> embU8 (fp8), 8 elems/thread
__global__ __launch_bounds__(256) void u8pack(
    const float* __restrict__ embU, u8* __restrict__ embU8)
{
    int t = blockIdx.x * 256 + threadIdx.x;
    if (t >= NVOCAB * HD / 8) return;
    float u[8];
    *(float4*)&u[0] = *(const float4*)&embU[t * 8];
    *(float4*)&u[4] = *(const float4*)&embU[t * 8 + 4];
    u32x2 o = pack8fp8(u);
    *(u32x2*)&embU8[t * 8] = o;
}

// weights: fragment-packed (Wz_p, Wh_p, Ur_p, Wo_p).
__global__ __launch_bounds__(256) void prep_wt(
    const float* __restrict__ Ur_w, const float* __restrict__ Wz_w,
    const float* __restrict__ Wh_w, const float* __restrict__ out_w,
    ush* __restrict__ Wo_p,
    ush* __restrict__ Wz_p, ush* __restrict__ Wh_p, ush* __restrict__ Ur_p)
{
    int idx = blockIdx.x * 256 + threadIdx.x;   // n*256 + k
    int n = idx >> 8, k = idx & 255;
    int paddr = ((((n >> 4) * 8 + (k >> 5)) * 64 + ((k >> 3) & 3) * 16 + (n & 15)) << 3) + (k & 7);
    Wo_p[paddr] = f2bf_fast(out_w[(HD + k) * HD + n]);
    Wz_p[paddr] = f2bf_fast(Wz_w[(HD + k) * HD + n]);
    Wh_p[paddr] = f2bf_fast(Wh_w[(HD + k) * HD + n]);
    Ur_p[paddr] = f2bf_fast(Ur_w[k * HD + n]);
}

__global__ __launch_bounds__(256) void prep_vmess(
    const int* __restrict__ fnode, const int* __restrict__ fmess,
    int* __restrict__ v_mess)
{
    int m = blockIdx.x * 256 + threadIdx.x;
    v_mess[m] = fnode[fmess[m]];
}

// ---------------- fused step: gather + Z/P GEMM + GRU + U-GEMM --------------
// 32 messages/block, 256 threads (4 waves), LDS 33.8 KiB -> 4 blocks/CU.
// TAB=1 (depth-1): neighbor rows come from the L2-resident vocab tables
// (h1tab bf16 / embU8 fp8) via v_mess[j]; HM is not read.
template<int EMIT_HU, int TAB>
__global__ __launch_bounds__(256, 4) void fused_step(
    const u8* __restrict__ HM, const int* __restrict__ mg,
    const int* __restrict__ v_mess,
    const ush* __restrict__ h1tab, const u8* __restrict__ embU8,
    const float* __restrict__ embR, const float* __restrict__ embZ,
    const float* __restrict__ embH,
    const ush* __restrict__ Wz_p, const ush* __restrict__ Wh_p,
    const ush* __restrict__ Ur_p,
    u8* __restrict__ HM_next)
{
    __shared__ __align__(16) ush sh[BMF * LDF];   // sum_h tile  (16.9 KiB)
    __shared__ __align__(16) ush sg[BMF * LDF];   // sum_gh -> h_next tile
    int tid = threadIdx.x;
    int wv = tid >> 6, lane = tid & 63;
    int quad = lane >> 4, l16 = lane & 15;
    int m0 = blockIdx.x * BMF;

    // ---- phase 1: gather + r-gate into LDS ----
    #pragma unroll 2
    for (int it = 0; it < 4; it++) {
        int g = it * 256 + tid;
        int ml = g >> 5;               // 0..31
        int c = (g & 31) * 8;          // 0..248
        int m = m0 + ml;
        int v = v_mess[m];
        float rb[8];
        *(float4*)&rb[0] = *(const float4*)&embR[v * HD + c];
        *(float4*)&rb[4] = *(const float4*)&embR[v * HD + c + 4];
        float ah[8] = {0,0,0,0,0,0,0,0};
        float ag[8] = {0,0,0,0,0,0,0,0};
        #pragma unroll
        for (int kn = 0; kn < MAXNEI; kn++) {
            int j = mg[m * MAXNEI + kn];
            s16x8 hv;
            u32x2 uv8;
            float msk;
            if (TAB) {
                int vmj = v_mess[j];
                hv = *(const s16x8*)&h1tab[vmj * HD + c];
                uv8 = *(const u32x2*)&embU8[vmj * HD + c];
                msk = (j != 0) ? 1.f : 0.f;   // message 0 is padding (h=0)
            } else {
                const u8* row = HM + (size_t)j * ROWB;
                hv = *(const s16x8*)(row + 2 * c);
                uv8 = *(const u32x2*)(row + 512 + c);
                msk = 1.f;
            }
            float uf[8];
            fp8x8_to_f32(uv8, uf);
            #pragma unroll
            for (int e = 0; e < 8; e++) {
                float hf = bf2f((ush)hv[e]) * msk;
                ah[e] += hf;
                ag[e] += sigm(rb[e] + uf[e]) * hf;
            }
        }
        uint4 oh, og;
        oh.x = pack2bf(ah[1], ah[0]); oh.y = pack2bf(ah[3], ah[2]);
        oh.z = pack2bf(ah[5], ah[4]); oh.w = pack2bf(ah[7], ah[6]);
        og.x = pack2bf(ag[1], ag[0]); og.y = pack2bf(ag[3], ag[2]);
        og.z = pack2bf(ag[5], ag[4]); og.w = pack2bf(ag[7], ag[6]);
        *(uint4*)&sh[ml * LDF + c] = oh;
        *(uint4*)&sg[ml * LDF + c] = og;
    }
    __syncthreads();

    // ---- phase 2: Z = sum_h @ Wz2, P = sum_gh @ Wh2 (B frags from global) ----
    f32x4v az[2][4] = {}, ap[2][4] = {};
    #pragma unroll
    for (int ksi = 0; ksi < 8; ksi++) {
        int ks = ksi * 32;
        bfrag ahf[2], agf[2], bz[4], bh[4];
        #pragma unroll
        for (int i = 0; i < 2; i++) {
            ahf[i] = *(const bfrag*)&sh[(i * 16 + l16) * LDF + ks + quad * 8];
            agf[i] = *(const bfrag*)&sg[(i * 16 + l16) * LDF + ks + quad * 8];
        }
        #pragma unroll
        for (int j = 0; j < 4; j++) {
            int f = ((wv * 4 + j) * 8 + ksi) * 64 + lane;
            bz[j] = *(const bfrag*)&Wz_p[(size_t)f * 8];
            bh[j] = *(const bfrag*)&Wh_p[(size_t)f * 8];
        }
        #pragma unroll
        for (int i = 0; i < 2; i++)
            #pragma unroll
            for (int j = 0; j < 4; j++) {
                az[i][j] = __builtin_amdgcn_mfma_f32_16x16x32_bf16(ahf[i], bz[j], az[i][j], 0, 0, 0);
                ap[i][j] = __builtin_amdgcn_mfma_f32_16x16x32_bf16(agf[i], bh[j], ap[i][j], 0, 0, 0);
            }
    }

    // ---- GRU combine: az[i][j][r] <- h_next value (reuse regs) ----
    #pragma unroll
    for (int i = 0; i < 2; i++) {
        #pragma unroll
        for (int r = 0; r < 4; r++) {
            int rl = i * 16 + quad * 4 + r;
            int Rg = m0 + rl;
            int v = v_mess[Rg];
            #pragma unroll
            for (int j = 0; j < 4; j++) {
                int col = wv * 64 + j * 16 + l16;
                float z = sigm(az[i][j][r] + embZ[v * HD + col]);
                float pre = tanh_fast(ap[i][j][r] + embH[v * HD + col]);
                float shv = bf2f(sh[rl * LDF + col]);
                float hn = (1.f - z) * shv + z * pre;
                if (Rg == 0) hn = 0.f;
                az[i][j][r] = hn;
            }
        }
    }
    __syncthreads();   // all sh/sg reads done

    // ---- h_next tile into sg (LDS), then coalesced bf16 global write ----
    #pragma unroll
    for (int i = 0; i < 2; i++)
        #pragma unroll
        for (int j = 0; j < 4; j++) {
            int col = wv * 64 + j * 16 + l16;
            #pragma unroll
            for (int r = 0; r < 4; r++)
                sg[(i * 16 + quad * 4 + r) * LDF + col] = f2bf_fast(az[i][j][r]);
        }
    __syncthreads();
    #pragma unroll
    for (int it = 0; it < 4; it++) {
        int g = it * 256 + tid;
        int ml = g >> 5;
        int c = (g & 31) * 8;
        *(uint4*)(HM_next + (size_t)(m0 + ml) * ROWB + 2 * c) =
            *(const uint4*)&sg[ml * LDF + c];
    }

    if (EMIT_HU) {
        // ---- U-GEMM: hU_next = h_next @ Ur  (A frags from sg, bf16) ----
        f32x4v au[2][4] = {};
        #pragma unroll
        for (int ksi = 0; ksi < 8; ksi++) {
            int ks = ksi * 32;
            bfrag af[2], bu[4];
            #pragma unroll
            for (int i = 0; i < 2; i++)
                af[i] = *(const bfrag*)&sg[(i * 16 + l16) * LDF + ks + quad * 8];
            #pragma unroll
            for (int j = 0; j < 4; j++) {
                int f = ((wv * 4 + j) * 8 + ksi) * 64 + lane;
                bu[j] = *(const bfrag*)&Ur_p[(size_t)f * 8];
            }
            #pragma unroll
            for (int i = 0; i < 2; i++)
                #pragma unroll
                for (int j = 0; j < 4; j++)
                    au[i][j] = __builtin_amdgcn_mfma_f32_16x16x32_bf16(af[i], bu[j], au[i][j], 0, 0, 0);
        }
        // write au (bf16) into sh, then coalesced fp8 pack + store
        #pragma unroll
        for (int i = 0; i < 2; i++)
            #pragma unroll
            for (int j = 0; j < 4; j++) {
                int col = wv * 64 + j * 16 + l16;
                #pragma unroll
                for (int r = 0; r < 4; r++)
                    sh[(i * 16 + quad * 4 + r) * LDF + col] = f2bf_fast(au[i][j][r]);
            }
        __syncthreads();
        #pragma unroll
        for (int it = 0; it < 4; it++) {
            int g = it * 256 + tid;
            int ml = g >> 5;
            int c = (g & 31) * 8;
            uint4 w = *(const uint4*)&sh[ml * LDF + c];
            float f[8] = { bfu_lo(w.x), bfu_hi(w.x), bfu_lo(w.y), bfu_hi(w.y),
                           bfu_lo(w.z), bfu_hi(w.z), bfu_lo(w.w), bfu_hi(w.w) };
            u32x2 o = pack8fp8(f);
            *(u32x2*)(HM_next + (size_t)(m0 + ml) * ROWB + 512 + c) = o;
        }
    }
}

// ---------------- fused tail: node gather + out-projection GEMM -------------
__global__ __launch_bounds__(256) void gather_out(
    const u8* __restrict__ HM, const int* __restrict__ ng,
    const int* __restrict__ fnode, const float* __restrict__ embO,
    const ush* __restrict__ Wo_p, float* __restrict__ node_vec)
{
    __shared__ __align__(16) ush sh[BMF * LDF];
    int tid = threadIdx.x;
    int wv = tid >> 6, lane = tid & 63;
    int quad = lane >> 4, l16 = lane & 15;
    int n0 = blockIdx.x * BMF;

    #pragma unroll 2
    for (int it = 0; it < 4; it++) {
        int g = it * 256 + tid;
        int ml = g >> 5;
        int c = (g & 31) * 8;
        int n = n0 + ml;
        float a[8] = {0,0,0,0,0,0,0,0};
        #pragma unroll
        for (int kn = 0; kn < MAXNEI; kn++) {
            int j = ng[n * MAXNEI + kn];
            s16x8 hv = *(const s16x8*)(HM + (size_t)j * ROWB + 2 * c);
            #pragma unroll
            for (int e = 0; e < 8; e++) a[e] += bf2f((ush)hv[e]);
        }
        uint4 o;
        o.x = pack2bf(a[1], a[0]); o.y = pack2bf(a[3], a[2]);
        o.z = pack2bf(a[5], a[4]); o.w = pack2bf(a[7], a[6]);
        *(uint4*)&sh[ml * LDF + c] = o;
    }
    __syncthreads();

    f32x4v acc[2][4] = {};
    #pragma unroll
    for (int ksi = 0; ksi < 8; ksi++) {
        int ks = ksi * 32;
        bfrag af[2], bo[4];
        #pragma unroll
        for (int i = 0; i < 2; i++)
            af[i] = *(const bfrag*)&sh[(i * 16 + l16) * LDF + ks + quad * 8];
        #pragma unroll
        for (int j = 0; j < 4; j++) {
            int f = ((wv * 4 + j) * 8 + ksi) * 64 + lane;
            bo[j] = *(const bfrag*)&Wo_p[(size_t)f * 8];
        }
        #pragma unroll
        for (int i = 0; i < 2; i++)
            #pragma unroll
            for (int j = 0; j < 4; j++)
                acc[i][j] = __builtin_amdgcn_mfma_f32_16x16x32_bf16(af[i], bo[j], acc[i][j], 0, 0, 0);
    }

    #pragma unroll
    for (int i = 0; i < 2; i++) {
        #pragma unroll
        for (int r = 0; r < 4; r++) {
            int Rn = n0 + i * 16 + quad * 4 + r;
            int v = fnode[Rn];
            #pragma unroll
            for (int j = 0; j < 4; j++) {
                int col = wv * 64 + j * 16 + l16;
                float o = acc[i][j][r] + embO[v * HD + col];
                node_vec[(size_t)Rn * HD + col] = fmaxf(o, 0.f);
            }
        }
    }
}

// ---------------- per-tree segment mean (scope_ids sorted) ------------------
__device__ __forceinline__ int lower_bound_dev(const int* a, int n, int key) {
    int lo = 0, hi = n;
    while (lo < hi) { int mid = (lo + hi) >> 1; if (a[mid] < key) lo = mid + 1; else hi = mid; }
    return lo;
}

__global__ __launch_bounds__(256) void segment_mean(
    const float* __restrict__ node_vec, const int* __restrict__ scope,
    float* __restrict__ out)
{
    int t = blockIdx.x;
    int c = threadIdx.x;
    int lo = lower_bound_dev(scope, NNODES, t);
    int hi = lower_bound_dev(scope, NNODES, t + 1);
    float acc = 0.f;
    for (int n = lo; n < hi; n++) acc += node_vec[(size_t)n * HD + c];
    int cnt = hi - lo;
    out[t * HD + c] = cnt > 0 ? acc / (float)cnt : 0.f;
}

// ---------------------------------------------------------------------------
extern "C" void kernel_launch(void* const* d_in, const int* in_sizes, int n_in,
                              void* d_out, int out_size, void* d_ws, size_t ws_size,
                              hipStream_t stream)
{
    const int*   fnode      = (const int*)d_in[0];
    const int*   fmess      = (const int*)d_in[1];
    const int*   node_graph = (const int*)d_in[2];
    const int*   mess_graph = (const int*)d_in[3];
    const int*   scope_ids  = (const int*)d_in[4];
    const float* emb        = (const float*)d_in[5];
    const float* Wz_w       = (const float*)d_in[6];
    const float* Wz_b       = (const float*)d_in[7];
    const float* Wr_w       = (const float*)d_in[8];
    const float* Ur_w       = (const float*)d_in[9];
    const float* Ur_b       = (const float*)d_in[10];
    const float* Wh_w       = (const float*)d_in[11];
    const float* Wh_b       = (const float*)d_in[12];
    const float* out_w      = (const float*)d_in[13];
    const float* out_b      = (const float*)d_in[14];

    // ---- workspace carve (~198 MiB) ----
    char* ws = (char*)d_ws;
    const size_t HMB = (size_t)NMESS * ROWB;           // 100.7 MB combined row buf
    u8* HM0 = (u8*)ws; ws += HMB;                      // ping
    u8* HM1 = (u8*)ws; ws += HMB;                      // pong
    float* embR = (float*)ws; ws += (size_t)NVOCAB * HD * 4;
    float* embZ = (float*)ws; ws += (size_t)NVOCAB * HD * 4;
    float* embH = (float*)ws; ws += (size_t)NVOCAB * HD * 4;
    float* embO = (float*)ws; ws += (size_t)NVOCAB * HD * 4;
    float* embU = (float*)ws; ws += (size_t)NVOCAB * HD * 4;
    ush* h1tab = (ush*)ws; ws += (size_t)NVOCAB * HD * 2;
    u8* embU8  = (u8*)ws;  ws += (size_t)NVOCAB * HD;
    ush* Wo_p  = (ush*)ws; ws += (size_t)HD * HD * 2;
    ush* Wz_p  = (ush*)ws; ws += (size_t)HD * HD * 2;
    ush* Wh_p  = (ush*)ws; ws += (size_t)HD * HD * 2;
    ush* Ur_p  = (ush*)ws; ws += (size_t)HD * HD * 2;
    int* v_mess = (int*)ws; ws += (size_t)NMESS * 4;
    if ((size_t)(ws - (char*)d_ws) > ws_size) return;  // fail loud, not fault

    hipMemsetAsync(embR, 0, (size_t)5 * NVOCAB * HD * 4, stream);  // embR..embU
    prep_tables_sk<<<dim3(NVOCAB / 4, 4), 256, 0, stream>>>(
        emb, Wz_w, Wz_b, Wr_w, Ur_b, Wh_w, Wh_b, out_w, out_b,
        embR, embZ, embH, embO);
    h1fill<<<NVOCAB, 256, 0, stream>>>(embZ, embH, h1tab);
    h1u_sk<<<dim3(NVOCAB / 4, 4), 256, 0, stream>>>(h1tab, Ur_w, embU);
    u8pack<<<(NVOCAB * HD / 8 + 255) / 256, 256, 0, stream>>>(embU, embU8);
    prep_wt<<<HD * HD / 256, 256, 0, stream>>>(Ur_w, Wz_w, Wh_w, out_w,
                                               Wo_p, Wz_p, Wh_p, Ur_p);
    prep_vmess<<<NMESS / 256, 256, 0, stream>>>(fnode, fmess, v_mess);

    // depth-1: table gather (h1/hU1 are vocab-table rows; no HM read, no fill)
    fused_step<1, 1><<<NMESS / BMF, 256, 0, stream>>>(
        nullptr, mess_graph, v_mess, h1tab, embU8,
        embR, embZ, embH, Wz_p, Wh_p, Ur_p, HM0);
    u8* hc = HM0; u8* hn = HM1;
    for (int d = 2; d < 5; d++) {
        fused_step<1, 0><<<NMESS / BMF, 256, 0, stream>>>(
            hc, mess_graph, v_mess, nullptr, nullptr,
            embR, embZ, embH, Wz_p, Wh_p, Ur_p, hn);
        u8* t = hc; hc = hn; hn = t;
    }
    fused_step<0, 0><<<NMESS / BMF, 256, 0, stream>>>(
        hc, mess_graph, v_mess, nullptr, nullptr,
        embR, embZ, embH, Wz_p, Wh_p, Ur_p, hn);
    hc = hn;  // final HM (h part valid); the other buffer is free

    float* node_vec = (float*)(hc == HM0 ? HM1 : HM0);  // 67 MB < 100.7 MB ✓
    gather_out<<<NNODES / BMF, 256, 0, stream>>>(hc, node_graph, fnode, embO,
                                                 Wo_p, node_vec);
    segment_mean<<<NTREES, 256, 0, stream>>>(node_vec, scope_ids, (float*)d_out);
}

// Round 14
// 1020.711 us; speedup vs baseline: 1.6789x; 1.0145x over previous
//
#include <hip/hip_runtime.h>

// JTNN encoder, MI355X.
//  - hU = h @ Ur_w once per row, gathered (5x FLOP cut vs h_nei@Ur)
//  - h bf16 (fp8-h FAILED accuracy R7); hU fp8 e4m3 (validated safe R6)
//  - h + hU interleaved in ONE 768 B/row buffer HM (single random fetch/neighbor)
//  - R10 NT stores / R11 reg-cap / R12 LDS-shrink: all disproven; R9 config
//    (LDF=264 pad, bounds(256,4), plain stores) is the steady-step champion.
//  - R13: depth-1 gathers L2-resident vocab tables, fill_h1 eliminated; but
//    mg->v_mess->table dependent chain made it 206us. R14: vmn[] precompute
//    (vmn = v_mess[mg], with padding mapped to a ZERO table row NVOCAB) cuts
//    the chain to vmn->table.
//  - fused_step: gather + Z/P GEMM + GRU update + U-GEMM in ONE kernel
//  - gather_out: node-side gather + out-projection GEMM fused

#define HD 256
#define NNODES 65536
#define NMESS 131072
#define NVOCAB 780
#define NTREES 2048
#define MAXNEI 5
#define BMF 32
#define LDF 264     // padded LDS stride (shorts)
#define ROWB 768    // HM row bytes: 512 h-bf16 + 256 u-fp8

typedef short bfrag __attribute__((ext_vector_type(8)));   // 8 bf16 in 4 VGPRs
typedef short s16x8 __attribute__((ext_vector_type(8)));
typedef float f32x4v __attribute__((ext_vector_type(4)));
typedef float f32x2 __attribute__((ext_vector_type(2)));
typedef unsigned int u32x2 __attribute__((ext_vector_type(2)));
typedef unsigned short ush;
typedef unsigned char u8;

__device__ __forceinline__ float bf2f(ush u) {
    union { unsigned int u; float f; } v; v.u = ((unsigned int)u) << 16; return v.f;
}
__device__ __forceinline__ float bfu_lo(unsigned int w) {
    union { unsigned int u; float f; } v; v.u = w << 16; return v.f;
}
__device__ __forceinline__ float bfu_hi(unsigned int w) {
    union { unsigned int u; float f; } v; v.u = w & 0xffff0000u; return v.f;
}
__device__ __forceinline__ ush f2bf_fast(float f) {
    union { float f; unsigned int u; } v; v.f = f;
    return (ush)((v.u + 0x8000u) >> 16);
}
__device__ __forceinline__ unsigned int pack2bf(float hi, float lo) {
    union { float f; unsigned int u; } a, b; a.f = hi; b.f = lo;
    return __builtin_amdgcn_perm(a.u + 0x8000u, b.u + 0x8000u, 0x07060302u);
}
__device__ __forceinline__ float sigm(float x) {
    return __builtin_amdgcn_rcpf(1.f + __expf(-x));
}
__device__ __forceinline__ float tanh_fast(float x) {
    return 1.f - 2.f * __builtin_amdgcn_rcpf(__expf(2.f * x) + 1.f);
}
// 8 f32 -> 8 fp8 e4m3 packed in u32x2
__device__ __forceinline__ u32x2 pack8fp8(const float* f) {
    int lo = __builtin_amdgcn_cvt_pk_fp8_f32(f[0], f[1], 0, 0);
    lo = __builtin_amdgcn_cvt_pk_fp8_f32(f[2], f[3], lo, 1);
    int hi = __builtin_amdgcn_cvt_pk_fp8_f32(f[4], f[5], 0, 0);
    hi = __builtin_amdgcn_cvt_pk_fp8_f32(f[6], f[7], hi, 1);
    u32x2 o; o.x = (unsigned int)lo; o.y = (unsigned int)hi; return o;
}
// 8 fp8 e4m3 (u32x2) -> 8 f32
__device__ __forceinline__ void fp8x8_to_f32(u32x2 v, float* f) {
    f32x2 a = __builtin_amdgcn_cvt_pk_f32_fp8((int)v.x, false);
    f32x2 b = __builtin_amdgcn_cvt_pk_f32_fp8((int)v.x, true);
    f32x2 c = __builtin_amdgcn_cvt_pk_f32_fp8((int)v.y, false);
    f32x2 d = __builtin_amdgcn_cvt_pk_f32_fp8((int)v.y, true);
    f[0] = a.x; f[1] = a.y; f[2] = b.x; f[3] = b.y;
    f[4] = c.x; f[5] = c.y; f[6] = d.x; f[7] = d.y;
}

// ---------------- prep: vocab tables, split-k over 4 blocks (atomicAdd) -----
__global__ __launch_bounds__(256) void prep_tables_sk(
    const float* __restrict__ emb,
    const float* __restrict__ Wz_w, const float* __restrict__ Wz_b,
    const float* __restrict__ Wr_w, const float* __restrict__ Ur_b,
    const float* __restrict__ Wh_w, const float* __restrict__ Wh_b,
    const float* __restrict__ out_w, const float* __restrict__ out_b,
    float* __restrict__ embR, float* __restrict__ embZ,
    float* __restrict__ embH, float* __restrict__ embO)
{
    __shared__ __align__(16) float e[4][64];
    int t = threadIdx.x;
    int b0 = blockIdx.x * 4;
    int k0 = blockIdx.y * 64;
    e[t >> 6][t & 63] = emb[(b0 + (t >> 6)) * HD + k0 + (t & 63)];
    __syncthreads();
    float aR[4] = {0,0,0,0}, aZ[4] = {0,0,0,0}, aH[4] = {0,0,0,0}, aO[4] = {0,0,0,0};
    for (int kk = 0; kk < 64; kk++) {
        int k = k0 + kk;
        float wr = Wr_w[k * HD + t];
        float wz = Wz_w[k * HD + t];
        float wh = Wh_w[k * HD + t];
        float wo = out_w[k * HD + t];
        #pragma unroll
        for (int r = 0; r < 4; r++) {
            float ev = e[r][kk];
            aR[r] += ev * wr; aZ[r] += ev * wz; aH[r] += ev * wh; aO[r] += ev * wo;
        }
    }
    if (blockIdx.y == 0) {
        float br = Ur_b[t], bz = Wz_b[t], bh = Wh_b[t], bo = out_b[t];
        #pragma unroll
        for (int r = 0; r < 4; r++) { aR[r] += br; aZ[r] += bz; aH[r] += bh; aO[r] += bo; }
    }
    #pragma unroll
    for (int r = 0; r < 4; r++) {
        atomicAdd(&embR[(b0 + r) * HD + t], aR[r]);
        atomicAdd(&embZ[(b0 + r) * HD + t], aZ[r]);
        atomicAdd(&embH[(b0 + r) * HD + t], aH[r]);
        atomicAdd(&embO[(b0 + r) * HD + t], aO[r]);
    }
}

// h1tab[v] = sigmoid(embZ[v]) * tanh(embH[v]); row NVOCAB = 0 (padding row)
__global__ __launch_bounds__(256) void h1fill(
    const float* __restrict__ embZ, const float* __restrict__ embH,
    ush* __restrict__ h1tab)
{
    int i = blockIdx.x * HD + threadIdx.x;
    if (blockIdx.x == NVOCAB) { h1tab[i] = 0; return; }
    h1tab[i] = f2bf_fast(sigm(embZ[i]) * tanh_fast(embH[i]));
}

// embU[v] = h1tab[v] @ Ur_w  (780x256 rows, split-k atomic)
__global__ __launch_bounds__(256) void h1u_sk(
    const ush* __restrict__ h1tab, const float* __restrict__ Ur_w,
    float* __restrict__ embU)
{
    __shared__ __align__(16) float e[4][64];
    int t = threadIdx.x;
    int b0 = blockIdx.x * 4;
    int k0 = blockIdx.y * 64;
    e[t >> 6][t & 63] = bf2f(h1tab[(b0 + (t >> 6)) * HD + k0 + (t & 63)]);
    __syncthreads();
    float aU[4] = {0,0,0,0};
    for (int kk = 0; kk < 64; kk++) {
        float w = Ur_w[(k0 + kk) * HD + t];
        #pragma unroll
        for (int r = 0; r < 4; r++) aU[r] += e[r][kk] * w;
    }
    #pragma unroll
    for (int r = 0; r < 4; r++) atomicAdd(&embU[(b0 + r) * HD + t], aU[r]);
}

// pack embU (f32) -> embU8 (fp8), 8 elems/thread; row NVOCAB zeroed
__global__ __launch_bounds__(256) void u8pack(
    const float* __restrict__ embU, u8* __restrict__ embU8)
{
    int t = blockIdx.x * 256 + threadIdx.x;
    if (t >= (NVOCAB + 1) * HD / 8) return;
    u32x2 o;
    if (t >= NVOCAB * HD / 8) {
        o.x = 0; o.y = 0;
    } else {
        float u[8];
        *(float4*)&u[0] = *(const float4*)&embU[t * 8];
        *(float4*)&u[4] = *(const float4*)&embU[t * 8 + 4];
        o = pack8fp8(u);
    }
    *(u32x2*)&embU8[t * 8] = o;
}

// weights: fragment-packed (Wz_p, Wh_p, Ur_p, Wo_p).
__global__ __launch_bounds__(256) void prep_wt(
    const float* __restrict__ Ur_w, const float* __restrict__ Wz_w,
    const float* __restrict__ Wh_w, const float* __restrict__ out_w,
    ush* __restrict__ Wo_p,
    ush* __restrict__ Wz_p, ush* __restrict__ Wh_p, ush* __restrict__ Ur_p)
{
    int idx = blockIdx.x * 256 + threadIdx.x;   // n*256 + k
    int n = idx >> 8, k = idx & 255;
    int paddr = ((((n >> 4) * 8 + (k >> 5)) * 64 + ((k >> 3) & 3) * 16 + (n & 15)) << 3) + (k & 7);
    Wo_p[paddr] = f2bf_fast(out_w[(HD + k) * HD + n]);
    Wz_p[paddr] = f2bf_fast(Wz_w[(HD + k) * HD + n]);
    Wh_p[paddr] = f2bf_fast(Wh_w[(HD + k) * HD + n]);
    Ur_p[paddr] = f2bf_fast(Ur_w[k * HD + n]);
}

__global__ __launch_bounds__(256) void prep_vmess(
    const int* __restrict__ fnode, const int* __restrict__ fmess,
    int* __restrict__ v_mess)
{
    int m = blockIdx.x * 256 + threadIdx.x;
    v_mess[m] = fnode[fmess[m]];
}

// vmn[i] = vocab id of neighbor message mg[i]; padding (mg==0) -> zero row
__global__ __launch_bounds__(256) void prep_vmn(
    const int* __restrict__ mg, const int* __restrict__ v_mess,
    int* __restrict__ vmn)
{
    int i = blockIdx.x * 256 + threadIdx.x;
    if (i >= NMESS * MAXNEI) return;
    int j = mg[i];
    vmn[i] = (j == 0) ? NVOCAB : v_mess[j];
}

// ---------------- fused step: gather + Z/P GEMM + GRU + U-GEMM --------------
// 32 messages/block, 256 threads (4 waves), LDS 33.8 KiB -> 4 blocks/CU.
// TAB=1 (depth-1): neighbor rows come straight from the L2-resident vocab
// tables via precomputed vmn[] (no mg->v_mess dependent chain, no mask:
// padding maps to zero row NVOCAB).
template<int EMIT_HU, int TAB>
__global__ __launch_bounds__(256, 4) void fused_step(
    const u8* __restrict__ HM, const int* __restrict__ mg,
    const int* __restrict__ vmn, const int* __restrict__ v_mess,
    const ush* __restrict__ h1tab, const u8* __restrict__ embU8,
    const float* __restrict__ embR, const float* __restrict__ embZ,
    const float* __restrict__ embH,
    const ush* __restrict__ Wz_p, const ush* __restrict__ Wh_p,
    const ush* __restrict__ Ur_p,
    u8* __restrict__ HM_next)
{
    __shared__ __align__(16) ush sh[BMF * LDF];   // sum_h tile  (16.9 KiB)
    __shared__ __align__(16) ush sg[BMF * LDF];   // sum_gh -> h_next tile
    int tid = threadIdx.x;
    int wv = tid >> 6, lane = tid & 63;
    int quad = lane >> 4, l16 = lane & 15;
    int m0 = blockIdx.x * BMF;

    // ---- phase 1: gather + r-gate into LDS ----
    #pragma unroll 2
    for (int it = 0; it < 4; it++) {
        int g = it * 256 + tid;
        int ml = g >> 5;               // 0..31
        int c = (g & 31) * 8;          // 0..248
        int m = m0 + ml;
        int v = v_mess[m];
        int jj[MAXNEI];
        #pragma unroll
        for (int kn = 0; kn < MAXNEI; kn++)
            jj[kn] = TAB ? vmn[m * MAXNEI + kn] : mg[m * MAXNEI + kn];
        float rb[8];
        *(float4*)&rb[0] = *(const float4*)&embR[v * HD + c];
        *(float4*)&rb[4] = *(const float4*)&embR[v * HD + c + 4];
        float ah[8] = {0,0,0,0,0,0,0,0};
        float ag[8] = {0,0,0,0,0,0,0,0};
        #pragma unroll
        for (int kn = 0; kn < MAXNEI; kn++) {
            int j = jj[kn];
            s16x8 hv;
            u32x2 uv8;
            if (TAB) {
                hv = *(const s16x8*)&h1tab[j * HD + c];
                uv8 = *(const u32x2*)&embU8[j * HD + c];
            } else {
                const u8* row = HM + (size_t)j * ROWB;
                hv = *(const s16x8*)(row + 2 * c);
                uv8 = *(const u32x2*)(row + 512 + c);
            }
            float uf[8];
            fp8x8_to_f32(uv8, uf);
            #pragma unroll
            for (int e = 0; e < 8; e++) {
                float hf = bf2f((ush)hv[e]);
                ah[e] += hf;
                ag[e] += sigm(rb[e] + uf[e]) * hf;
            }
        }
        uint4 oh, og;
        oh.x = pack2bf(ah[1], ah[0]); oh.y = pack2bf(ah[3], ah[2]);
        oh.z = pack2bf(ah[5], ah[4]); oh.w = pack2bf(ah[7], ah[6]);
        og.x = pack2bf(ag[1], ag[0]); og.y = pack2bf(ag[3], ag[2]);
        og.z = pack2bf(ag[5], ag[4]); og.w = pack2bf(ag[7], ag[6]);
        *(uint4*)&sh[ml * LDF + c] = oh;
        *(uint4*)&sg[ml * LDF + c] = og;
    }
    __syncthreads();

    // ---- phase 2: Z = sum_h @ Wz2, P = sum_gh @ Wh2 (B frags from global) ----
    f32x4v az[2][4] = {}, ap[2][4] = {};
    #pragma unroll
    for (int ksi = 0; ksi < 8; ksi++) {
        int ks = ksi * 32;
        bfrag ahf[2], agf[2], bz[4], bh[4];
        #pragma unroll
        for (int i = 0; i < 2; i++) {
            ahf[i] = *(const bfrag*)&sh[(i * 16 + l16) * LDF + ks + quad * 8];
            agf[i] = *(const bfrag*)&sg[(i * 16 + l16) * LDF + ks + quad * 8];
        }
        #pragma unroll
        for (int j = 0; j < 4; j++) {
            int f = ((wv * 4 + j) * 8 + ksi) * 64 + lane;
            bz[j] = *(const bfrag*)&Wz_p[(size_t)f * 8];
            bh[j] = *(const bfrag*)&Wh_p[(size_t)f * 8];
        }
        #pragma unroll
        for (int i = 0; i < 2; i++)
            #pragma unroll
            for (int j = 0; j < 4; j++) {
                az[i][j] = __builtin_amdgcn_mfma_f32_16x16x32_bf16(ahf[i], bz[j], az[i][j], 0, 0, 0);
                ap[i][j] = __builtin_amdgcn_mfma_f32_16x16x32_bf16(agf[i], bh[j], ap[i][j], 0, 0, 0);
            }
    }

    // ---- GRU combine: az[i][j][r] <- h_next value (reuse regs) ----
    #pragma unroll
    for (int i = 0; i < 2; i++) {
        #pragma unroll
        for (int r = 0; r < 4; r++) {
            int rl = i * 16 + quad * 4 + r;
            int Rg = m0 + rl;
            int v = v_mess[Rg];
            #pragma unroll
            for (int j = 0; j < 4; j++) {
                int col = wv * 64 + j * 16 + l16;
                float z = sigm(az[i][j][r] + embZ[v * HD + col]);
                float pre = tanh_fast(ap[i][j][r] + embH[v * HD + col]);
                float shv = bf2f(sh[rl * LDF + col]);
                float hn = (1.f - z) * shv + z * pre;
                if (Rg == 0) hn = 0.f;
                az[i][j][r] = hn;
            }
        }
    }
    __syncthreads();   // all sh/sg reads done

    // ---- h_next tile into sg (LDS), then coalesced bf16 global write ----
    #pragma unroll
    for (int i = 0; i < 2; i++)
        #pragma unroll
        for (int j = 0; j < 4; j++) {
            int col = wv * 64 + j * 16 + l16;
            #pragma unroll
            for (int r = 0; r < 4; r++)
                sg[(i * 16 + quad * 4 + r) * LDF + col] = f2bf_fast(az[i][j][r]);
        }
    __syncthreads();
    #pragma unroll
    for (int it = 0; it < 4; it++) {
        int g = it * 256 + tid;
        int ml = g >> 5;
        int c = (g & 31) * 8;
        *(uint4*)(HM_next + (size_t)(m0 + ml) * ROWB + 2 * c) =
            *(const uint4*)&sg[ml * LDF + c];
    }

    if (EMIT_HU) {
        // ---- U-GEMM: hU_next = h_next @ Ur  (A frags from sg, bf16) ----
        f32x4v au[2][4] = {};
        #pragma unroll
        for (int ksi = 0; ksi < 8; ksi++) {
            int ks = ksi * 32;
            bfrag af[2], bu[4];
            #pragma unroll
            for (int i = 0; i < 2; i++)
                af[i] = *(const bfrag*)&sg[(i * 16 + l16) * LDF + ks + quad * 8];
            #pragma unroll
            for (int j = 0; j < 4; j++) {
                int f = ((wv * 4 + j) * 8 + ksi) * 64 + lane;
                bu[j] = *(const bfrag*)&Ur_p[(size_t)f * 8];
            }
            #pragma unroll
            for (int i = 0; i < 2; i++)
                #pragma unroll
                for (int j = 0; j < 4; j++)
                    au[i][j] = __builtin_amdgcn_mfma_f32_16x16x32_bf16(af[i], bu[j], au[i][j], 0, 0, 0);
        }
        // write au (bf16) into sh, then coalesced fp8 pack + store
        #pragma unroll
        for (int i = 0; i < 2; i++)
            #pragma unroll
            for (int j = 0; j < 4; j++) {
                int col = wv * 64 + j * 16 + l16;
                #pragma unroll
                for (int r = 0; r < 4; r++)
                    sh[(i * 16 + quad * 4 + r) * LDF + col] = f2bf_fast(au[i][j][r]);
            }
        __syncthreads();
        #pragma unroll
        for (int it = 0; it < 4; it++) {
            int g = it * 256 + tid;
            int ml = g >> 5;
            int c = (g & 31) * 8;
            uint4 w = *(const uint4*)&sh[ml * LDF + c];
            float f[8] = { bfu_lo(w.x), bfu_hi(w.x), bfu_lo(w.y), bfu_hi(w.y),
                           bfu_lo(w.z), bfu_hi(w.z), bfu_lo(w.w), bfu_hi(w.w) };
            u32x2 o = pack8fp8(f);
            *(u32x2*)(HM_next + (size_t)(m0 + ml) * ROWB + 512 + c) = o;
        }
    }
}

// ---------------- fused tail: node gather + out-projection GEMM -------------
__global__ __launch_bounds__(256) void gather_out(
    const u8* __restrict__ HM, const int* __restrict__ ng,
    const int* __restrict__ fnode, const float* __restrict__ embO,
    const ush* __restrict__ Wo_p, float* __restrict__ node_vec)
{
    __shared__ __align__(16) ush sh[BMF * LDF];
    int tid = threadIdx.x;
    int wv = tid >> 6, lane = tid & 63;
    int quad = lane >> 4, l16 = lane & 15;
    int n0 = blockIdx.x * BMF;

    #pragma unroll 2
    for (int it = 0; it < 4; it++) {
        int g = it * 256 + tid;
        int ml = g >> 5;
        int c = (g & 31) * 8;
        int n = n0 + ml;
        float a[8] = {0,0,0,0,0,0,0,0};
        #pragma unroll
        for (int kn = 0; kn < MAXNEI; kn++) {
            int j = ng[n * MAXNEI + kn];
            s16x8 hv = *(const s16x8*)(HM + (size_t)j * ROWB + 2 * c);
            #pragma unroll
            for (int e = 0; e < 8; e++) a[e] += bf2f((ush)hv[e]);
        }
        uint4 o;
        o.x = pack2bf(a[1], a[0]); o.y = pack2bf(a[3], a[2]);
        o.z = pack2bf(a[5], a[4]); o.w = pack2bf(a[7], a[6]);
        *(uint4*)&sh[ml * LDF + c] = o;
    }
    __syncthreads();

    f32x4v acc[2][4] = {};
    #pragma unroll
    for (int ksi = 0; ksi < 8; ksi++) {
        int ks = ksi * 32;
        bfrag af[2], bo[4];
        #pragma unroll
        for (int i = 0; i < 2; i++)
            af[i] = *(const bfrag*)&sh[(i * 16 + l16) * LDF + ks + quad * 8];
        #pragma unroll
        for (int j = 0; j < 4; j++) {
            int f = ((wv * 4 + j) * 8 + ksi) * 64 + lane;
            bo[j] = *(const bfrag*)&Wo_p[(size_t)f * 8];
        }
        #pragma unroll
        for (int i = 0; i < 2; i++)
            #pragma unroll
            for (int j = 0; j < 4; j++)
                acc[i][j] = __builtin_amdgcn_mfma_f32_16x16x32_bf16(af[i], bo[j], acc[i][j], 0, 0, 0);
    }

    #pragma unroll
    for (int i = 0; i < 2; i++) {
        #pragma unroll
        for (int r = 0; r < 4; r++) {
            int Rn = n0 + i * 16 + quad * 4 + r;
            int v = fnode[Rn];
            #pragma unroll
            for (int j = 0; j < 4; j++) {
                int col = wv * 64 + j * 16 + l16;
                float o = acc[i][j][r] + embO[v * HD + col];
                node_vec[(size_t)Rn * HD + col] = fmaxf(o, 0.f);
            }
        }
    }
}

// ---------------- per-tree segment mean (scope_ids sorted) ------------------
__device__ __forceinline__ int lower_bound_dev(const int* a, int n, int key) {
    int lo = 0, hi = n;
    while (lo < hi) { int mid = (lo + hi) >> 1; if (a[mid] < key) lo = mid + 1; else hi = mid; }
    return lo;
}

__global__ __launch_bounds__(256) void segment_mean(
    const float* __restrict__ node_vec, const int* __restrict__ scope,
    float* __restrict__ out)
{
    int t = blockIdx.x;
    int c = threadIdx.x;
    int lo = lower_bound_dev(scope, NNODES, t);
    int hi = lower_bound_dev(scope, NNODES, t + 1);
    float acc = 0.f;
    for (int n = lo; n < hi; n++) acc += node_vec[(size_t)n * HD + c];
    int cnt = hi - lo;
    out[t * HD + c] = cnt > 0 ? acc / (float)cnt : 0.f;
}

// ---------------------------------------------------------------------------
extern "C" void kernel_launch(void* const* d_in, const int* in_sizes, int n_in,
                              void* d_out, int out_size, void* d_ws, size_t ws_size,
                              hipStream_t stream)
{
    const int*   fnode      = (const int*)d_in[0];
    const int*   fmess      = (const int*)d_in[1];
    const int*   node_graph = (const int*)d_in[2];
    const int*   mess_graph = (const int*)d_in[3];
    const int*   scope_ids  = (const int*)d_in[4];
    const float* emb        = (const float*)d_in[5];
    const float* Wz_w       = (const float*)d_in[6];
    const float* Wz_b       = (const float*)d_in[7];
    const float* Wr_w       = (const float*)d_in[8];
    const float* Ur_w       = (const float*)d_in[9];
    const float* Ur_b       = (const float*)d_in[10];
    const float* Wh_w       = (const float*)d_in[11];
    const float* Wh_b       = (const float*)d_in[12];
    const float* out_w      = (const float*)d_in[13];
    const float* out_b      = (const float*)d_in[14];

    // ---- workspace carve (~210 MiB) ----
    char* ws = (char*)d_ws;
    const size_t HMB = (size_t)NMESS * ROWB;           // 100.7 MB combined row buf
    u8* HM0 = (u8*)ws; ws += HMB;                      // ping
    u8* HM1 = (u8*)ws; ws += HMB;                      // pong
    float* embR = (float*)ws; ws += (size_t)NVOCAB * HD * 4;
    float* embZ = (float*)ws; ws += (size_t)NVOCAB * HD * 4;
    float* embH = (float*)ws; ws += (size_t)NVOCAB * HD * 4;
    float* embO = (float*)ws; ws += (size_t)NVOCAB * HD * 4;
    float* embU = (float*)ws; ws += (size_t)NVOCAB * HD * 4;
    ush* h1tab = (ush*)ws; ws += (size_t)(NVOCAB + 1) * HD * 2;
    u8* embU8  = (u8*)ws;  ws += (size_t)(NVOCAB + 1) * HD;
    ush* Wo_p  = (ush*)ws; ws += (size_t)HD * HD * 2;
    ush* Wz_p  = (ush*)ws; ws += (size_t)HD * HD * 2;
    ush* Wh_p  = (ush*)ws; ws += (size_t)HD * HD * 2;
    ush* Ur_p  = (ush*)ws; ws += (size_t)HD * HD * 2;
    int* v_mess = (int*)ws; ws += (size_t)NMESS * 4;
    int* vmn    = (int*)ws; ws += (size_t)NMESS * MAXNEI * 4;
    if ((size_t)(ws - (char*)d_ws) > ws_size) return;  // fail loud, not fault

    hipMemsetAsync(embR, 0, (size_t)5 * NVOCAB * HD * 4, stream);  // embR..embU
    prep_tables_sk<<<dim3(NVOCAB / 4, 4), 256, 0, stream>>>(
        emb, Wz_w, Wz_b, Wr_w, Ur_b, Wh_w, Wh_b, out_w, out_b,
        embR, embZ, embH, embO);
    h1fill<<<NVOCAB + 1, 256, 0, stream>>>(embZ, embH, h1tab);
    h1u_sk<<<dim3(NVOCAB / 4, 4), 256, 0, stream>>>(h1tab, Ur_w, embU);
    u8pack<<<((NVOCAB + 1) * HD / 8 + 255) / 256, 256, 0, stream>>>(embU, embU8);
    prep_wt<<<HD * HD / 256, 256, 0, stream>>>(Ur_w, Wz_w, Wh_w, out_w,
                                               Wo_p, Wz_p, Wh_p, Ur_p);
    prep_vmess<<<NMESS / 256, 256, 0, stream>>>(fnode, fmess, v_mess);
    prep_vmn<<<(NMESS * MAXNEI + 255) / 256, 256, 0, stream>>>(mess_graph, v_mess, vmn);

    // depth-1: direct vocab-table gather via vmn (no HM read, no fill)
    fused_step<1, 1><<<NMESS / BMF, 256, 0, stream>>>(
        nullptr, mess_graph, vmn, v_mess, h1tab, embU8,
        embR, embZ, embH, Wz_p, Wh_p, Ur_p, HM0);
    u8* hc = HM0; u8* hn = HM1;
    for (int d = 2; d < 5; d++) {
        fused_step<1, 0><<<NMESS / BMF, 256, 0, stream>>>(
            hc, mess_graph, nullptr, v_mess, nullptr, nullptr,
            embR, embZ, embH, Wz_p, Wh_p, Ur_p, hn);
        u8* t = hc; hc = hn; hn = t;
    }
    fused_step<0, 0><<<NMESS / BMF, 256, 0, stream>>>(
        hc, mess_graph, nullptr, v_mess, nullptr, nullptr,
        embR, embZ, embH, Wz_p, Wh_p, Ur_p, hn);
    hc = hn;  // final HM (h part valid); the other buffer is free

    float* node_vec = (float*)(hc == HM0 ? HM1 : HM0);  // 67 MB < 100.7 MB ✓
    gather_out<<<NNODES / BMF, 256, 0, stream>>>(hc, node_graph, fnode, embO,
                                                 Wo_p, node_vec);
    segment_mean<<<NTREES, 256, 0, stream>>>(node_vec, scope_ids, (float*)d_out);
}